// Round 1
// baseline (3189.423 us; speedup 1.0000x reference)
//
#include <hip/hip_runtime.h>
#include <hip/hip_bf16.h>

// Problem constants
#define Bsz   16
#define Tn    2048
#define INC   80
#define Hc    512
#define Dc    512
#define NCODE 1024
#define RECON_N (Bsz * Tn * INC)   // 2,621,440

// ---------------------------------------------------------------------------
// code_norms: CN[j] = sum_d CB[j][d]^2
// ---------------------------------------------------------------------------
__global__ __launch_bounds__(64)
void code_norms(const float* __restrict__ CB, float* __restrict__ CN) {
    int j = blockIdx.x;
    int lane = threadIdx.x;
    const float4* row = (const float4*)(CB + (size_t)j * Dc);
    float s = 0.f;
    #pragma unroll
    for (int i = 0; i < 2; ++i) {
        float4 v = row[lane + i * 64];
        s = fmaf(v.x, v.x, s);
        s = fmaf(v.y, v.y, s);
        s = fmaf(v.z, v.z, s);
        s = fmaf(v.w, v.w, s);
    }
    #pragma unroll
    for (int off = 32; off > 0; off >>= 1) s += __shfl_down(s, off, 64);
    if (lane == 0) CN[j] = s;
}

// ---------------------------------------------------------------------------
// conv_enc1: mels [B,T,80] -> Y [B,512,T], K=3 SAME, ReLU fused at store.
// grid: (T/64, 512/64, B), block 256
// ---------------------------------------------------------------------------
__global__ __launch_bounds__(256)
void conv_enc1(const float* __restrict__ X, const float* __restrict__ W,
               const float* __restrict__ bias, float* __restrict__ Y) {
    const int t0 = blockIdx.x * 64;
    const int o0 = blockIdx.y * 64;
    const int b  = blockIdx.z;
    __shared__ float Xs[16][72];   // [c][t(-1..64)], pad 72 (16B-aligned rows)
    __shared__ float Ws[48][68];   // [c*3+k][o], pad 68 (16B-aligned rows)
    const int tid = threadIdx.x;
    const int tx = tid & 15, ty = tid >> 4;
    float acc[4][4] = {};

    for (int c0 = 0; c0 < INC; c0 += 16) {
        // stage X tile (transpose from [T,80] layout), halo of 1 on each side
        for (int i = tid; i < 16 * 66; i += 256) {
            int tt = i / 16, cc = i % 16;
            int t = t0 + tt - 1;
            float v = 0.f;
            if (t >= 0 && t < Tn) v = X[((size_t)b * Tn + t) * INC + c0 + cc];
            Xs[cc][tt] = v;
        }
        // stage W tile transposed: W[o][c][k] row-major -> Ws[ck][o]
        for (int i = tid; i < 64 * 48; i += 256) {
            int o = i / 48, ck = i % 48;
            Ws[ck][o] = W[((size_t)(o0 + o) * INC + c0) * 3 + ck];
        }
        __syncthreads();
        #pragma unroll
        for (int cc = 0; cc < 16; ++cc) {
            float x[6];
            #pragma unroll
            for (int j = 0; j < 6; ++j) x[j] = Xs[cc][tx * 4 + j];
            #pragma unroll
            for (int k = 0; k < 3; ++k) {
                float w0 = Ws[cc * 3 + k][ty * 4 + 0];
                float w1 = Ws[cc * 3 + k][ty * 4 + 1];
                float w2 = Ws[cc * 3 + k][ty * 4 + 2];
                float w3 = Ws[cc * 3 + k][ty * 4 + 3];
                #pragma unroll
                for (int j = 0; j < 4; ++j) {
                    float xv = x[k + j];
                    acc[0][j] = fmaf(w0, xv, acc[0][j]);
                    acc[1][j] = fmaf(w1, xv, acc[1][j]);
                    acc[2][j] = fmaf(w2, xv, acc[2][j]);
                    acc[3][j] = fmaf(w3, xv, acc[3][j]);
                }
            }
        }
        __syncthreads();
    }
    float* Yb = Y + (size_t)b * Hc * Tn;
    #pragma unroll
    for (int i = 0; i < 4; ++i) {
        int o = o0 + ty * 4 + i;
        float bv = bias[o];
        #pragma unroll
        for (int j = 0; j < 4; ++j) {
            float v = acc[i][j] + bv;
            v = fmaxf(v, 0.f);   // ReLU fused (encoder conv1 output feeds conv2)
            Yb[(size_t)o * Tn + t0 + tx * 4 + j] = v;
        }
    }
}

// ---------------------------------------------------------------------------
// conv_mid: X [B,512,T] -> Y [B,512,T], K=3 SAME. RELU template = relu@store.
// grid: (T/64, 512/64, B), block 256
// ---------------------------------------------------------------------------
template <int RELU>
__global__ __launch_bounds__(256)
void conv_mid(const float* __restrict__ X, const float* __restrict__ W,
              const float* __restrict__ bias, float* __restrict__ Y) {
    const int t0 = blockIdx.x * 64;
    const int o0 = blockIdx.y * 64;
    const int b  = blockIdx.z;
    __shared__ float Xs[16][72];
    __shared__ float Ws[48][68];
    const int tid = threadIdx.x;
    const int tx = tid & 15, ty = tid >> 4;
    float acc[4][4] = {};
    const float* Xb = X + (size_t)b * Hc * Tn;

    for (int c0 = 0; c0 < Hc; c0 += 16) {
        for (int i = tid; i < 16 * 66; i += 256) {
            int cc = i / 66, tt = i % 66;
            int t = t0 + tt - 1;
            float v = 0.f;
            if (t >= 0 && t < Tn) v = Xb[(size_t)(c0 + cc) * Tn + t];
            Xs[cc][tt] = v;
        }
        for (int i = tid; i < 64 * 48; i += 256) {
            int o = i / 48, ck = i % 48;
            Ws[ck][o] = W[((size_t)(o0 + o) * Hc + c0) * 3 + ck];
        }
        __syncthreads();
        #pragma unroll
        for (int cc = 0; cc < 16; ++cc) {
            float x[6];
            #pragma unroll
            for (int j = 0; j < 6; ++j) x[j] = Xs[cc][tx * 4 + j];
            #pragma unroll
            for (int k = 0; k < 3; ++k) {
                float w0 = Ws[cc * 3 + k][ty * 4 + 0];
                float w1 = Ws[cc * 3 + k][ty * 4 + 1];
                float w2 = Ws[cc * 3 + k][ty * 4 + 2];
                float w3 = Ws[cc * 3 + k][ty * 4 + 3];
                #pragma unroll
                for (int j = 0; j < 4; ++j) {
                    float xv = x[k + j];
                    acc[0][j] = fmaf(w0, xv, acc[0][j]);
                    acc[1][j] = fmaf(w1, xv, acc[1][j]);
                    acc[2][j] = fmaf(w2, xv, acc[2][j]);
                    acc[3][j] = fmaf(w3, xv, acc[3][j]);
                }
            }
        }
        __syncthreads();
    }
    float* Yb = Y + (size_t)b * Hc * Tn;
    #pragma unroll
    for (int i = 0; i < 4; ++i) {
        int o = o0 + ty * 4 + i;
        float bv = bias[o];
        #pragma unroll
        for (int j = 0; j < 4; ++j) {
            float v = acc[i][j] + bv;
            if (RELU) v = fmaxf(v, 0.f);
            Yb[(size_t)o * Tn + t0 + tx * 4 + j] = v;
        }
    }
}

// ---------------------------------------------------------------------------
// conv_dec2: X [B,512,T] -> recon [B,T,80], K=3 SAME, masked output channels.
// grid: (T/64, 2, B), block 256
// ---------------------------------------------------------------------------
__global__ __launch_bounds__(256)
void conv_dec2(const float* __restrict__ X, const float* __restrict__ W,
               const float* __restrict__ bias, float* __restrict__ OUT) {
    const int t0 = blockIdx.x * 64;
    const int o0 = blockIdx.y * 64;
    const int b  = blockIdx.z;
    __shared__ float Xs[16][72];
    __shared__ float Ws[48][68];
    const int tid = threadIdx.x;
    const int tx = tid & 15, ty = tid >> 4;
    float acc[4][4] = {};
    const float* Xb = X + (size_t)b * Hc * Tn;

    for (int c0 = 0; c0 < Hc; c0 += 16) {
        for (int i = tid; i < 16 * 66; i += 256) {
            int cc = i / 66, tt = i % 66;
            int t = t0 + tt - 1;
            float v = 0.f;
            if (t >= 0 && t < Tn) v = Xb[(size_t)(c0 + cc) * Tn + t];
            Xs[cc][tt] = v;
        }
        for (int i = tid; i < 64 * 48; i += 256) {
            int o = i / 48, ck = i % 48;
            int oo = o0 + o;
            Ws[ck][o] = (oo < INC) ? W[((size_t)oo * Hc + c0) * 3 + ck] : 0.f;
        }
        __syncthreads();
        #pragma unroll
        for (int cc = 0; cc < 16; ++cc) {
            float x[6];
            #pragma unroll
            for (int j = 0; j < 6; ++j) x[j] = Xs[cc][tx * 4 + j];
            #pragma unroll
            for (int k = 0; k < 3; ++k) {
                float w0 = Ws[cc * 3 + k][ty * 4 + 0];
                float w1 = Ws[cc * 3 + k][ty * 4 + 1];
                float w2 = Ws[cc * 3 + k][ty * 4 + 2];
                float w3 = Ws[cc * 3 + k][ty * 4 + 3];
                #pragma unroll
                for (int j = 0; j < 4; ++j) {
                    float xv = x[k + j];
                    acc[0][j] = fmaf(w0, xv, acc[0][j]);
                    acc[1][j] = fmaf(w1, xv, acc[1][j]);
                    acc[2][j] = fmaf(w2, xv, acc[2][j]);
                    acc[3][j] = fmaf(w3, xv, acc[3][j]);
                }
            }
        }
        __syncthreads();
    }
    #pragma unroll
    for (int i = 0; i < 4; ++i) {
        int o = o0 + ty * 4 + i;
        if (o < INC) {
            float bv = bias[o];
            #pragma unroll
            for (int j = 0; j < 4; ++j) {
                float v = acc[i][j] + bv;
                OUT[((size_t)b * Tn + (t0 + tx * 4 + j)) * INC + o] = v;
            }
        }
    }
}

// ---------------------------------------------------------------------------
// vq_argmin: Z [B,512,T]; argmin_j ( CN[j] - 2 * z.c_j ). Writes int idx to ws
// and float idx to d_out tail. grid: (T/64, B), block 256
// ---------------------------------------------------------------------------
__global__ __launch_bounds__(256)
void vq_argmin(const float* __restrict__ Z, const float* __restrict__ CB,
               const float* __restrict__ CN, int* __restrict__ idx_out,
               float* __restrict__ idxf_out) {
    const int t0 = blockIdx.x * 64;
    const int b  = blockIdx.y;
    const int tid = threadIdx.x;
    const int tx = tid & 15, ty = tid >> 4;   // tx -> 4 positions, ty -> 4 codes
    __shared__ float Zs[32][68];
    __shared__ float Cs[32][68];
    __shared__ float rv[64][17];
    __shared__ int   ri[64][17];

    float bestv[4];
    int   besti[4];
    #pragma unroll
    for (int p = 0; p < 4; ++p) { bestv[p] = 1e30f; besti[p] = 0; }

    const float* Zb = Z + (size_t)b * Dc * Tn + t0;

    for (int j0 = 0; j0 < NCODE; j0 += 64) {
        float acc[4][4] = {};
        for (int d0 = 0; d0 < Dc; d0 += 32) {
            // stage Z: [32 d][64 t], coalesced over t
            for (int i = tid; i < 32 * 64; i += 256) {
                int dd = i >> 6, tt = i & 63;
                Zs[dd][tt] = Zb[(size_t)(d0 + dd) * Tn + tt];
            }
            // stage codes transposed: CB[j][d] -> Cs[dd][j]
            for (int i = tid; i < 512; i += 256) {
                int j = i >> 3, dq = i & 7;
                const float4 v = *(const float4*)(CB + (size_t)(j0 + j) * Dc + d0 + dq * 4);
                Cs[dq * 4 + 0][j] = v.x;
                Cs[dq * 4 + 1][j] = v.y;
                Cs[dq * 4 + 2][j] = v.z;
                Cs[dq * 4 + 3][j] = v.w;
            }
            __syncthreads();
            #pragma unroll
            for (int dd = 0; dd < 32; ++dd) {
                float z0 = Zs[dd][tx * 4 + 0];
                float z1 = Zs[dd][tx * 4 + 1];
                float z2 = Zs[dd][tx * 4 + 2];
                float z3 = Zs[dd][tx * 4 + 3];
                float c0 = Cs[dd][ty * 4 + 0];
                float c1 = Cs[dd][ty * 4 + 1];
                float c2 = Cs[dd][ty * 4 + 2];
                float c3 = Cs[dd][ty * 4 + 3];
                acc[0][0] = fmaf(z0, c0, acc[0][0]); acc[0][1] = fmaf(z0, c1, acc[0][1]);
                acc[0][2] = fmaf(z0, c2, acc[0][2]); acc[0][3] = fmaf(z0, c3, acc[0][3]);
                acc[1][0] = fmaf(z1, c0, acc[1][0]); acc[1][1] = fmaf(z1, c1, acc[1][1]);
                acc[1][2] = fmaf(z1, c2, acc[1][2]); acc[1][3] = fmaf(z1, c3, acc[1][3]);
                acc[2][0] = fmaf(z2, c0, acc[2][0]); acc[2][1] = fmaf(z2, c1, acc[2][1]);
                acc[2][2] = fmaf(z2, c2, acc[2][2]); acc[2][3] = fmaf(z2, c3, acc[2][3]);
                acc[3][0] = fmaf(z3, c0, acc[3][0]); acc[3][1] = fmaf(z3, c1, acc[3][1]);
                acc[3][2] = fmaf(z3, c2, acc[3][2]); acc[3][3] = fmaf(z3, c3, acc[3][3]);
            }
            __syncthreads();
        }
        // fold this code tile into the running per-position min
        #pragma unroll
        for (int q = 0; q < 4; ++q) {
            int j = j0 + ty * 4 + q;
            float cnv = CN[j];
            #pragma unroll
            for (int p = 0; p < 4; ++p) {
                float dist = fmaf(-2.f, acc[p][q], cnv);
                if (dist < bestv[p] || (dist == bestv[p] && j < besti[p])) {
                    bestv[p] = dist; besti[p] = j;
                }
            }
        }
    }
    // cross-thread reduce over ty (16 code-groups) per position
    #pragma unroll
    for (int p = 0; p < 4; ++p) {
        rv[tx * 4 + p][ty] = bestv[p];
        ri[tx * 4 + p][ty] = besti[p];
    }
    __syncthreads();
    if (tid < 64) {
        float bv = rv[tid][0];
        int   bi = ri[tid][0];
        #pragma unroll
        for (int y = 1; y < 16; ++y) {
            float v = rv[tid][y];
            int   i2 = ri[tid][y];
            if (v < bv || (v == bv && i2 < bi)) { bv = v; bi = i2; }
        }
        int n = b * Tn + t0 + tid;
        idx_out[n] = bi;
        idxf_out[n] = (float)bi;
    }
}

// ---------------------------------------------------------------------------
// gather_q: Q[b][d][t] = CB[idx[b][t]][d]. grid: (T/64, B), block 256
// ---------------------------------------------------------------------------
__global__ __launch_bounds__(256)
void gather_q(const int* __restrict__ idx, const float* __restrict__ CB,
              float* __restrict__ Q) {
    const int t0 = blockIdx.x * 64;
    const int b  = blockIdx.y;
    const int tid = threadIdx.x;
    __shared__ int sidx[64];
    if (tid < 64) sidx[tid] = idx[b * Tn + t0 + tid];
    __syncthreads();
    for (int i = tid; i < 64 * 128; i += 256) {
        int tt = i & 63;
        int g  = i >> 6;              // d-group of 4
        int row = sidx[tt];
        const float4 v = *(const float4*)(CB + (size_t)row * Dc + g * 4);
        float* qp = Q + (size_t)b * Dc * Tn + (size_t)(g * 4) * Tn + t0 + tt;
        qp[0]        = v.x;
        qp[Tn]       = v.y;
        qp[2 * Tn]   = v.z;
        qp[3 * Tn]   = v.w;
    }
}

// ---------------------------------------------------------------------------
extern "C" void kernel_launch(void* const* d_in, const int* in_sizes, int n_in,
                              void* d_out, int out_size, void* d_ws, size_t ws_size,
                              hipStream_t stream) {
    const float* mels    = (const float*)d_in[0];
    const float* enc_w1  = (const float*)d_in[1];
    const float* enc_b1  = (const float*)d_in[2];
    const float* enc_w2  = (const float*)d_in[3];
    const float* enc_b2  = (const float*)d_in[4];
    const float* codebook= (const float*)d_in[5];
    const float* dec_w1  = (const float*)d_in[6];
    const float* dec_b1  = (const float*)d_in[7];
    const float* dec_w2  = (const float*)d_in[8];
    const float* dec_b2  = (const float*)d_in[9];

    float* out = (float*)d_out;
    float* recon = out;                 // [B,T,80]
    float* idxf  = out + RECON_N;       // [B,T] as float

    const size_t ACT = (size_t)Bsz * Hc * Tn;   // 16,777,216 floats (64 MB)
    float* bufA = (float*)d_ws;                 // y1 (relu'd), later q
    float* bufB = bufA + ACT;                   // z, later y3 (relu'd)
    int*   idxI = (int*)(bufB + ACT);           // [B*T]
    float* cn   = (float*)(idxI + Bsz * Tn);    // [NCODE]

    dim3 blk(256);
    // codebook norms
    code_norms<<<dim3(NCODE), dim3(64), 0, stream>>>(codebook, cn);
    // encoder
    conv_enc1<<<dim3(Tn / 64, Hc / 64, Bsz), blk, 0, stream>>>(mels, enc_w1, enc_b1, bufA);
    conv_mid<0><<<dim3(Tn / 64, Dc / 64, Bsz), blk, 0, stream>>>(bufA, enc_w2, enc_b2, bufB);
    // vector quantization
    vq_argmin<<<dim3(Tn / 64, Bsz), blk, 0, stream>>>(bufB, codebook, cn, idxI, idxf);
    gather_q<<<dim3(Tn / 64, Bsz), blk, 0, stream>>>(idxI, codebook, bufA);
    // decoder
    conv_mid<1><<<dim3(Tn / 64, Hc / 64, Bsz), blk, 0, stream>>>(bufA, dec_w1, dec_b1, bufB);
    conv_dec2<<<dim3(Tn / 64, 2, Bsz), blk, 0, stream>>>(bufB, dec_w2, dec_b2, recon);
}

// Round 2
// 2521.070 us; speedup vs baseline: 1.2651x; 1.2651x over previous
//
#include <hip/hip_runtime.h>
#include <hip/hip_bf16.h>

// Problem constants
#define Bsz   16
#define Tn    2048
#define INC   80
#define Hc    512
#define Dc    512
#define NCODE 1024
#define BT    (Bsz * Tn)           // 32768
#define RECON_N (Bsz * Tn * INC)   // 2,621,440

// ---------------------------------------------------------------------------
// code_norms: CN[j] = sum_d CB[j][d]^2
// ---------------------------------------------------------------------------
__global__ __launch_bounds__(64)
void code_norms(const float* __restrict__ CB, float* __restrict__ CN) {
    int j = blockIdx.x;
    int lane = threadIdx.x;
    const float4* row = (const float4*)(CB + (size_t)j * Dc);
    float s = 0.f;
    #pragma unroll
    for (int i = 0; i < 2; ++i) {
        float4 v = row[lane + i * 64];
        s = fmaf(v.x, v.x, s);
        s = fmaf(v.y, v.y, s);
        s = fmaf(v.z, v.z, s);
        s = fmaf(v.w, v.w, s);
    }
    #pragma unroll
    for (int off = 32; off > 0; off >>= 1) s += __shfl_down(s, off, 64);
    if (lane == 0) CN[j] = s;
}

// ---------------------------------------------------------------------------
// cb_transpose: CBt[d][j] = CB[j][d].  grid (NCODE/64, Dc/64), block 256
// ---------------------------------------------------------------------------
__global__ __launch_bounds__(256)
void cb_transpose(const float* __restrict__ CB, float* __restrict__ CBt) {
    const int j0 = blockIdx.x * 64;
    const int d0 = blockIdx.y * 64;
    __shared__ float ts[64][65];
    const int tid = threadIdx.x;
    for (int i = tid; i < 4096; i += 256) {
        int r = i >> 6, c = i & 63;
        ts[r][c] = CB[(size_t)(j0 + r) * Dc + d0 + c];
    }
    __syncthreads();
    for (int i = tid; i < 4096; i += 256) {
        int r = i >> 6, c = i & 63;
        CBt[(size_t)(d0 + r) * NCODE + j0 + c] = ts[c][r];
    }
}

// ---------------------------------------------------------------------------
// wt_transpose: Wt[(c*3+k)*Cout + o] = W[(o*Cin + c)*3 + k]
// grid (ceil(Cout/64), Cin/16), block 256
// ---------------------------------------------------------------------------
__global__ __launch_bounds__(256)
void wt_transpose(const float* __restrict__ W, float* __restrict__ Wt,
                  int Cin, int Cout) {
    const int o0 = blockIdx.x * 64;
    const int c0 = blockIdx.y * 16;
    __shared__ float ts[48][65];
    const int tid = threadIdx.x;
    for (int i = tid; i < 64 * 48; i += 256) {
        int o = i / 48, ck = i % 48;
        int oo = o0 + o;
        float v = 0.f;
        if (oo < Cout) v = W[(size_t)oo * Cin * 3 + c0 * 3 + ck];
        ts[ck][o] = v;
    }
    __syncthreads();
    for (int i = tid; i < 48 * 64; i += 256) {
        int o = i & 63, ck = i >> 6;
        int oo = o0 + o;
        if (oo < Cout) Wt[(size_t)(c0 * 3 + ck) * Cout + oo] = ts[ck][o];
    }
}

// ---------------------------------------------------------------------------
// conv_enc1: mels [B,T,80] -> Y [B,512,T], K=3 SAME, ReLU at store.
// Tile 64 t x 128 o; per-thread 4 t x 8 o. grid (T/64, 512/128, B), block 256
// ---------------------------------------------------------------------------
__global__ __launch_bounds__(256)
void conv_enc1(const float* __restrict__ X, const float* __restrict__ Wt,
               const float* __restrict__ bias, float* __restrict__ Y) {
    const int t0 = blockIdx.x * 64;
    const int o0 = blockIdx.y * 128;
    const int b  = blockIdx.z;
    __shared__ __align__(16) float Xs[16][72];
    __shared__ __align__(16) float Ws[48][132];
    const int tid = threadIdx.x;
    const int tx = tid & 15, ty = tid >> 4;
    float acc[8][4] = {};

    for (int c0 = 0; c0 < INC; c0 += 16) {
        for (int i = tid; i < 16 * 66; i += 256) {
            int cc = i / 66, tt = i % 66;
            int t = t0 + tt - 1;
            float v = 0.f;
            if (t >= 0 && t < Tn) v = X[((size_t)b * Tn + t) * INC + c0 + cc];
            Xs[cc][tt] = v;
        }
        for (int i = tid; i < 48 * 128; i += 256) {
            int o = i & 127, ck = i >> 7;
            Ws[ck][o] = Wt[(size_t)(c0 * 3 + ck) * Hc + o0 + o];
        }
        __syncthreads();
        #pragma unroll
        for (int cc = 0; cc < 16; ++cc) {
            float4 xa = *(const float4*)&Xs[cc][tx * 4];
            float2 xb2 = *(const float2*)&Xs[cc][tx * 4 + 4];
            float xv[6] = {xa.x, xa.y, xa.z, xa.w, xb2.x, xb2.y};
            #pragma unroll
            for (int k = 0; k < 3; ++k) {
                float4 wa = *(const float4*)&Ws[cc * 3 + k][ty * 8];
                float4 wb = *(const float4*)&Ws[cc * 3 + k][ty * 8 + 4];
                float wv[8] = {wa.x, wa.y, wa.z, wa.w, wb.x, wb.y, wb.z, wb.w};
                #pragma unroll
                for (int i8 = 0; i8 < 8; ++i8)
                    #pragma unroll
                    for (int j = 0; j < 4; ++j)
                        acc[i8][j] = fmaf(wv[i8], xv[k + j], acc[i8][j]);
            }
        }
        __syncthreads();
    }
    float* Yb = Y + (size_t)b * Hc * Tn;
    #pragma unroll
    for (int i8 = 0; i8 < 8; ++i8) {
        int o = o0 + ty * 8 + i8;
        float bv = bias[o];
        float4 r;
        r.x = fmaxf(acc[i8][0] + bv, 0.f);
        r.y = fmaxf(acc[i8][1] + bv, 0.f);
        r.z = fmaxf(acc[i8][2] + bv, 0.f);
        r.w = fmaxf(acc[i8][3] + bv, 0.f);
        *(float4*)&Yb[(size_t)o * Tn + t0 + tx * 4] = r;
    }
}

// ---------------------------------------------------------------------------
// conv_mid: X [B,512,T] -> Y [B,512,T], K=3 SAME. RELU template = relu@store.
// Tile 64 t x 128 o. grid (T/64, 512/128, B), block 256
// ---------------------------------------------------------------------------
template <int RELU>
__global__ __launch_bounds__(256)
void conv_mid(const float* __restrict__ X, const float* __restrict__ Wt,
              const float* __restrict__ bias, float* __restrict__ Y) {
    const int t0 = blockIdx.x * 64;
    const int o0 = blockIdx.y * 128;
    const int b  = blockIdx.z;
    __shared__ __align__(16) float Xs[16][72];
    __shared__ __align__(16) float Ws[48][132];
    const int tid = threadIdx.x;
    const int tx = tid & 15, ty = tid >> 4;
    float acc[8][4] = {};
    const float* Xb = X + (size_t)b * Hc * Tn;

    for (int c0 = 0; c0 < Hc; c0 += 16) {
        for (int i = tid; i < 16 * 66; i += 256) {
            int cc = i / 66, tt = i % 66;
            int t = t0 + tt - 1;
            float v = 0.f;
            if (t >= 0 && t < Tn) v = Xb[(size_t)(c0 + cc) * Tn + t];
            Xs[cc][tt] = v;
        }
        for (int i = tid; i < 48 * 128; i += 256) {
            int o = i & 127, ck = i >> 7;
            Ws[ck][o] = Wt[(size_t)(c0 * 3 + ck) * Hc + o0 + o];
        }
        __syncthreads();
        #pragma unroll
        for (int cc = 0; cc < 16; ++cc) {
            float4 xa = *(const float4*)&Xs[cc][tx * 4];
            float2 xb2 = *(const float2*)&Xs[cc][tx * 4 + 4];
            float xv[6] = {xa.x, xa.y, xa.z, xa.w, xb2.x, xb2.y};
            #pragma unroll
            for (int k = 0; k < 3; ++k) {
                float4 wa = *(const float4*)&Ws[cc * 3 + k][ty * 8];
                float4 wb = *(const float4*)&Ws[cc * 3 + k][ty * 8 + 4];
                float wv[8] = {wa.x, wa.y, wa.z, wa.w, wb.x, wb.y, wb.z, wb.w};
                #pragma unroll
                for (int i8 = 0; i8 < 8; ++i8)
                    #pragma unroll
                    for (int j = 0; j < 4; ++j)
                        acc[i8][j] = fmaf(wv[i8], xv[k + j], acc[i8][j]);
            }
        }
        __syncthreads();
    }
    float* Yb = Y + (size_t)b * Hc * Tn;
    #pragma unroll
    for (int i8 = 0; i8 < 8; ++i8) {
        int o = o0 + ty * 8 + i8;
        float bv = bias[o];
        float4 r;
        r.x = acc[i8][0] + bv;
        r.y = acc[i8][1] + bv;
        r.z = acc[i8][2] + bv;
        r.w = acc[i8][3] + bv;
        if (RELU) {
            r.x = fmaxf(r.x, 0.f); r.y = fmaxf(r.y, 0.f);
            r.z = fmaxf(r.z, 0.f); r.w = fmaxf(r.w, 0.f);
        }
        *(float4*)&Yb[(size_t)o * Tn + t0 + tx * 4] = r;
    }
}

// ---------------------------------------------------------------------------
// conv_dec2: X [B,512,T] -> recon [B,T,80]. Tile 64 t x 128 o (only 80 live).
// grid (T/64, 1, B), block 256
// ---------------------------------------------------------------------------
__global__ __launch_bounds__(256)
void conv_dec2(const float* __restrict__ X, const float* __restrict__ Wt,
               const float* __restrict__ bias, float* __restrict__ OUT) {
    const int t0 = blockIdx.x * 64;
    const int b  = blockIdx.z;
    __shared__ __align__(16) float Xs[16][72];
    __shared__ __align__(16) float Ws[48][132];
    const int tid = threadIdx.x;
    const int tx = tid & 15, ty = tid >> 4;
    float acc[8][4] = {};
    const float* Xb = X + (size_t)b * Hc * Tn;

    for (int c0 = 0; c0 < Hc; c0 += 16) {
        for (int i = tid; i < 16 * 66; i += 256) {
            int cc = i / 66, tt = i % 66;
            int t = t0 + tt - 1;
            float v = 0.f;
            if (t >= 0 && t < Tn) v = Xb[(size_t)(c0 + cc) * Tn + t];
            Xs[cc][tt] = v;
        }
        for (int i = tid; i < 48 * 128; i += 256) {
            int o = i & 127, ck = i >> 7;
            Ws[ck][o] = (o < INC) ? Wt[(size_t)(c0 * 3 + ck) * INC + o] : 0.f;
        }
        __syncthreads();
        #pragma unroll
        for (int cc = 0; cc < 16; ++cc) {
            float4 xa = *(const float4*)&Xs[cc][tx * 4];
            float2 xb2 = *(const float2*)&Xs[cc][tx * 4 + 4];
            float xv[6] = {xa.x, xa.y, xa.z, xa.w, xb2.x, xb2.y};
            #pragma unroll
            for (int k = 0; k < 3; ++k) {
                float4 wa = *(const float4*)&Ws[cc * 3 + k][ty * 8];
                float4 wb = *(const float4*)&Ws[cc * 3 + k][ty * 8 + 4];
                float wv[8] = {wa.x, wa.y, wa.z, wa.w, wb.x, wb.y, wb.z, wb.w};
                #pragma unroll
                for (int i8 = 0; i8 < 8; ++i8)
                    #pragma unroll
                    for (int j = 0; j < 4; ++j)
                        acc[i8][j] = fmaf(wv[i8], xv[k + j], acc[i8][j]);
            }
        }
        __syncthreads();
    }
    // output layout [B,T,80]: per thread 4 t x 8 consecutive o (ty<10 live)
    if (ty < 10) {
        float bv[8];
        #pragma unroll
        for (int i8 = 0; i8 < 8; ++i8) bv[i8] = bias[ty * 8 + i8];
        #pragma unroll
        for (int j = 0; j < 4; ++j) {
            int t = t0 + tx * 4 + j;
            float4 s0, s1;
            s0.x = acc[0][j] + bv[0]; s0.y = acc[1][j] + bv[1];
            s0.z = acc[2][j] + bv[2]; s0.w = acc[3][j] + bv[3];
            s1.x = acc[4][j] + bv[4]; s1.y = acc[5][j] + bv[5];
            s1.z = acc[6][j] + bv[6]; s1.w = acc[7][j] + bv[7];
            float* op = OUT + ((size_t)b * Tn + t) * INC + ty * 8;
            *(float4*)op = s0;
            *(float4*)(op + 4) = s1;
        }
    }
}

// ---------------------------------------------------------------------------
// vq_partial: per code-quarter partial argmin of CN[j] - 2 z.c_j.
// grid (T/64, B, 4), block 256. Per thread: 4 positions x 16 codes.
// ---------------------------------------------------------------------------
__global__ __launch_bounds__(256)
void vq_partial(const float* __restrict__ Z, const float* __restrict__ CBt,
                const float* __restrict__ CN, float* __restrict__ candv,
                int* __restrict__ candi) {
    const int t0 = blockIdx.x * 64;
    const int b  = blockIdx.y;
    const int jbase = blockIdx.z * 256;
    const int tid = threadIdx.x;
    const int tx = tid & 15, ty = tid >> 4;
    __shared__ __align__(16) float Zs[16][68];
    __shared__ __align__(16) float Cs[16][260];
    __shared__ float rv[64][17];
    __shared__ int   ri[64][17];

    float acc[16][4] = {};   // [code16][pos]
    const float* Zb = Z + (size_t)b * Dc * Tn + t0;

    for (int d0 = 0; d0 < Dc; d0 += 16) {
        for (int i = tid; i < 1024; i += 256) {
            int dd = i >> 6, tt = i & 63;
            Zs[dd][tt] = Zb[(size_t)(d0 + dd) * Tn + tt];
        }
        for (int i = tid; i < 1024; i += 256) {
            int dd = i >> 6, j4 = i & 63;
            *(float4*)&Cs[dd][j4 * 4] =
                *(const float4*)&CBt[(size_t)(d0 + dd) * NCODE + jbase + j4 * 4];
        }
        __syncthreads();
        #pragma unroll
        for (int dd = 0; dd < 16; ++dd) {
            float4 z = *(const float4*)&Zs[dd][tx * 4];
            float zp[4] = {z.x, z.y, z.z, z.w};
            #pragma unroll
            for (int s = 0; s < 4; ++s) {
                float4 c = *(const float4*)&Cs[dd][s * 64 + ty * 4];
                float cp[4] = {c.x, c.y, c.z, c.w};
                #pragma unroll
                for (int q = 0; q < 4; ++q)
                    #pragma unroll
                    for (int p = 0; p < 4; ++p)
                        acc[s * 4 + q][p] = fmaf(cp[q], zp[p], acc[s * 4 + q][p]);
            }
        }
        __syncthreads();
    }
    float bestv[4];
    int   besti[4];
    #pragma unroll
    for (int p = 0; p < 4; ++p) { bestv[p] = 1e30f; besti[p] = 0; }
    #pragma unroll
    for (int s = 0; s < 4; ++s)
        #pragma unroll
        for (int q = 0; q < 4; ++q) {
            int j = jbase + s * 64 + ty * 4 + q;
            float cnv = CN[j];
            #pragma unroll
            for (int p = 0; p < 4; ++p) {
                float dist = fmaf(-2.f, acc[s * 4 + q][p], cnv);
                if (dist < bestv[p] || (dist == bestv[p] && j < besti[p])) {
                    bestv[p] = dist; besti[p] = j;
                }
            }
        }
    #pragma unroll
    for (int p = 0; p < 4; ++p) {
        rv[tx * 4 + p][ty] = bestv[p];
        ri[tx * 4 + p][ty] = besti[p];
    }
    __syncthreads();
    if (tid < 64) {
        float bv = rv[tid][0];
        int   bi = ri[tid][0];
        #pragma unroll
        for (int y = 1; y < 16; ++y) {
            float v = rv[tid][y];
            int   i2 = ri[tid][y];
            if (v < bv || (v == bv && i2 < bi)) { bv = v; bi = i2; }
        }
        int n = b * Tn + t0 + tid;
        candv[(size_t)blockIdx.z * BT + n] = bv;
        candi[(size_t)blockIdx.z * BT + n] = bi;
    }
}

// ---------------------------------------------------------------------------
// vq_reduce: merge 4 candidates per position. grid (BT/256), block 256
// ---------------------------------------------------------------------------
__global__ __launch_bounds__(256)
void vq_reduce(const float* __restrict__ candv, const int* __restrict__ candi,
               int* __restrict__ idxI, float* __restrict__ idxf) {
    int n = blockIdx.x * 256 + threadIdx.x;
    float bv = candv[n];
    int   bi = candi[n];
    #pragma unroll
    for (int jq = 1; jq < 4; ++jq) {
        float v = candv[(size_t)jq * BT + n];
        int   i2 = candi[(size_t)jq * BT + n];
        if (v < bv || (v == bv && i2 < bi)) { bv = v; bi = i2; }
    }
    idxI[n] = bi;
    idxf[n] = (float)bi;
}

// ---------------------------------------------------------------------------
// gather_q: Q[b][d][t] = CB[idx[b][t]][d]. grid: (T/64, B), block 256
// ---------------------------------------------------------------------------
__global__ __launch_bounds__(256)
void gather_q(const int* __restrict__ idx, const float* __restrict__ CB,
              float* __restrict__ Q) {
    const int t0 = blockIdx.x * 64;
    const int b  = blockIdx.y;
    const int tid = threadIdx.x;
    __shared__ int sidx[64];
    if (tid < 64) sidx[tid] = idx[b * Tn + t0 + tid];
    __syncthreads();
    for (int i = tid; i < 64 * 128; i += 256) {
        int tt = i & 63;
        int g  = i >> 6;              // d-group of 4
        int row = sidx[tt];
        const float4 v = *(const float4*)(CB + (size_t)row * Dc + g * 4);
        float* qp = Q + (size_t)b * Dc * Tn + (size_t)(g * 4) * Tn + t0 + tt;
        qp[0]        = v.x;
        qp[Tn]       = v.y;
        qp[2 * Tn]   = v.z;
        qp[3 * Tn]   = v.w;
    }
}

// ---------------------------------------------------------------------------
extern "C" void kernel_launch(void* const* d_in, const int* in_sizes, int n_in,
                              void* d_out, int out_size, void* d_ws, size_t ws_size,
                              hipStream_t stream) {
    const float* mels    = (const float*)d_in[0];
    const float* enc_w1  = (const float*)d_in[1];
    const float* enc_b1  = (const float*)d_in[2];
    const float* enc_w2  = (const float*)d_in[3];
    const float* enc_b2  = (const float*)d_in[4];
    const float* codebook= (const float*)d_in[5];
    const float* dec_w1  = (const float*)d_in[6];
    const float* dec_b1  = (const float*)d_in[7];
    const float* dec_w2  = (const float*)d_in[8];
    const float* dec_b2  = (const float*)d_in[9];

    float* out = (float*)d_out;
    float* recon = out;                 // [B,T,80]
    float* idxf  = out + RECON_N;       // [B,T] as float

    const size_t ACT = (size_t)Bsz * Hc * Tn;   // 16,777,216 floats (64 MB)
    float* bufA = (float*)d_ws;                 // y1 (relu'd), later q
    float* bufB = bufA + ACT;                   // z, later y3 (relu'd)
    int*   idxI = (int*)(bufB + ACT);           // [B*T]
    float* cn   = (float*)(idxI + BT);          // [NCODE]
    float* cbt  = cn + NCODE;                   // [512*1024]
    float* wt1  = cbt + (size_t)Dc * NCODE;     // enc_w1t: 80*3*512
    float* wt2  = wt1 + (size_t)INC * 3 * Hc;   // enc_w2t: 512*3*512
    float* wt3  = wt2 + (size_t)Hc * 3 * Dc;    // dec_w1t: 512*3*512
    float* wt4  = wt3 + (size_t)Dc * 3 * Hc;    // dec_w2t: 512*3*80
    float* candv = wt4 + (size_t)Hc * 3 * INC;  // [4*BT]
    int*   candi = (int*)(candv + 4 * BT);      // [4*BT]

    dim3 blk(256);
    // prep: norms + transposes (cheap, every call — graph-capture safe)
    code_norms<<<dim3(NCODE), dim3(64), 0, stream>>>(codebook, cn);
    cb_transpose<<<dim3(NCODE / 64, Dc / 64), blk, 0, stream>>>(codebook, cbt);
    wt_transpose<<<dim3(Hc / 64, INC / 16), blk, 0, stream>>>(enc_w1, wt1, INC, Hc);
    wt_transpose<<<dim3(Dc / 64, Hc / 16), blk, 0, stream>>>(enc_w2, wt2, Hc, Dc);
    wt_transpose<<<dim3(Hc / 64, Dc / 16), blk, 0, stream>>>(dec_w1, wt3, Dc, Hc);
    wt_transpose<<<dim3(2, Hc / 16), blk, 0, stream>>>(dec_w2, wt4, Hc, INC);
    // encoder
    conv_enc1<<<dim3(Tn / 64, Hc / 128, Bsz), blk, 0, stream>>>(mels, wt1, enc_b1, bufA);
    conv_mid<0><<<dim3(Tn / 64, Dc / 128, Bsz), blk, 0, stream>>>(bufA, wt2, enc_b2, bufB);
    // vector quantization
    vq_partial<<<dim3(Tn / 64, Bsz, 4), blk, 0, stream>>>(bufB, cbt, cn, candv, candi);
    vq_reduce<<<dim3(BT / 256), blk, 0, stream>>>(candv, candi, idxI, idxf);
    gather_q<<<dim3(Tn / 64, Bsz), blk, 0, stream>>>(idxI, codebook, bufA);
    // decoder
    conv_mid<1><<<dim3(Tn / 64, Hc / 128, Bsz), blk, 0, stream>>>(bufA, wt3, dec_b1, bufB);
    conv_dec2<<<dim3(Tn / 64, 1, Bsz), blk, 0, stream>>>(bufB, wt4, dec_b2, recon);
}

// Round 3
// 1797.986 us; speedup vs baseline: 1.7739x; 1.4022x over previous
//
#include <hip/hip_runtime.h>
#include <hip/hip_bf16.h>

// Problem constants
#define Bsz   16
#define Tn    2048
#define INC   80
#define Hc    512
#define Dc    512
#define NCODE 1024
#define BT    (Bsz * Tn)           // 32768
#define RECON_N (Bsz * Tn * INC)   // 2,621,440

// ---------------------------------------------------------------------------
// code_norms: CN[j] = sum_d CB[j][d]^2
// ---------------------------------------------------------------------------
__global__ __launch_bounds__(64)
void code_norms(const float* __restrict__ CB, float* __restrict__ CN) {
    int j = blockIdx.x;
    int lane = threadIdx.x;
    const float4* row = (const float4*)(CB + (size_t)j * Dc);
    float s = 0.f;
    #pragma unroll
    for (int i = 0; i < 2; ++i) {
        float4 v = row[lane + i * 64];
        s = fmaf(v.x, v.x, s);
        s = fmaf(v.y, v.y, s);
        s = fmaf(v.z, v.z, s);
        s = fmaf(v.w, v.w, s);
    }
    #pragma unroll
    for (int off = 32; off > 0; off >>= 1) s += __shfl_down(s, off, 64);
    if (lane == 0) CN[j] = s;
}

// ---------------------------------------------------------------------------
// cb_transpose: CBt[d][j] = CB[j][d].  grid (NCODE/64, Dc/64), block 256
// ---------------------------------------------------------------------------
__global__ __launch_bounds__(256)
void cb_transpose(const float* __restrict__ CB, float* __restrict__ CBt) {
    const int j0 = blockIdx.x * 64;
    const int d0 = blockIdx.y * 64;
    __shared__ float ts[64][65];
    const int tid = threadIdx.x;
    for (int i = tid; i < 4096; i += 256) {
        int r = i >> 6, c = i & 63;
        ts[r][c] = CB[(size_t)(j0 + r) * Dc + d0 + c];
    }
    __syncthreads();
    for (int i = tid; i < 4096; i += 256) {
        int r = i >> 6, c = i & 63;
        CBt[(size_t)(d0 + r) * NCODE + j0 + c] = ts[c][r];
    }
}

// ---------------------------------------------------------------------------
// wt_transpose: Wt[(c*3+k)*Cout + o] = W[(o*Cin + c)*3 + k]
// grid (ceil(Cout/64), Cin/16), block 256
// ---------------------------------------------------------------------------
__global__ __launch_bounds__(256)
void wt_transpose(const float* __restrict__ W, float* __restrict__ Wt,
                  int Cin, int Cout) {
    const int o0 = blockIdx.x * 64;
    const int c0 = blockIdx.y * 16;
    __shared__ float ts[48][65];
    const int tid = threadIdx.x;
    for (int i = tid; i < 64 * 48; i += 256) {
        int o = i / 48, ck = i % 48;
        int oo = o0 + o;
        float v = 0.f;
        if (oo < Cout) v = W[(size_t)oo * Cin * 3 + c0 * 3 + ck];
        ts[ck][o] = v;
    }
    __syncthreads();
    for (int i = tid; i < 48 * 64; i += 256) {
        int o = i & 63, ck = i >> 6;
        int oo = o0 + o;
        if (oo < Cout) Wt[(size_t)(c0 * 3 + ck) * Cout + oo] = ts[ck][o];
    }
}

// ---------------------------------------------------------------------------
// conv_enc1: mels [B,T,80] -> Y [B,512,T], K=3 SAME, ReLU at store.
// Tile 64 t x 128 o; per-thread 4 t x 8 o. grid (T/64, 512/128, B), block 256
// ---------------------------------------------------------------------------
__global__ __launch_bounds__(256)
void conv_enc1(const float* __restrict__ X, const float* __restrict__ Wt,
               const float* __restrict__ bias, float* __restrict__ Y) {
    const int t0 = blockIdx.x * 64;
    const int o0 = blockIdx.y * 128;
    const int b  = blockIdx.z;
    __shared__ __align__(16) float Xs[16][72];
    __shared__ __align__(16) float Ws[48][132];
    const int tid = threadIdx.x;
    const int tx = tid & 15, ty = tid >> 4;
    float acc[8][4] = {};

    for (int c0 = 0; c0 < INC; c0 += 16) {
        for (int i = tid; i < 16 * 66; i += 256) {
            int cc = i / 66, tt = i % 66;
            int t = t0 + tt - 1;
            float v = 0.f;
            if (t >= 0 && t < Tn) v = X[((size_t)b * Tn + t) * INC + c0 + cc];
            Xs[cc][tt] = v;
        }
        for (int i = tid; i < 48 * 128; i += 256) {
            int o = i & 127, ck = i >> 7;
            Ws[ck][o] = Wt[(size_t)(c0 * 3 + ck) * Hc + o0 + o];
        }
        __syncthreads();
        #pragma unroll
        for (int cc = 0; cc < 16; ++cc) {
            float4 xa = *(const float4*)&Xs[cc][tx * 4];
            float2 xb2 = *(const float2*)&Xs[cc][tx * 4 + 4];
            float xv[6] = {xa.x, xa.y, xa.z, xa.w, xb2.x, xb2.y};
            #pragma unroll
            for (int k = 0; k < 3; ++k) {
                float4 wa = *(const float4*)&Ws[cc * 3 + k][ty * 8];
                float4 wb = *(const float4*)&Ws[cc * 3 + k][ty * 8 + 4];
                float wv[8] = {wa.x, wa.y, wa.z, wa.w, wb.x, wb.y, wb.z, wb.w};
                #pragma unroll
                for (int i8 = 0; i8 < 8; ++i8)
                    #pragma unroll
                    for (int j = 0; j < 4; ++j)
                        acc[i8][j] = fmaf(wv[i8], xv[k + j], acc[i8][j]);
            }
        }
        __syncthreads();
    }
    float* Yb = Y + (size_t)b * Hc * Tn;
    #pragma unroll
    for (int i8 = 0; i8 < 8; ++i8) {
        int o = o0 + ty * 8 + i8;
        float bv = bias[o];
        float4 r;
        r.x = fmaxf(acc[i8][0] + bv, 0.f);
        r.y = fmaxf(acc[i8][1] + bv, 0.f);
        r.z = fmaxf(acc[i8][2] + bv, 0.f);
        r.w = fmaxf(acc[i8][3] + bv, 0.f);
        *(float4*)&Yb[(size_t)o * Tn + t0 + tx * 4] = r;
    }
}

// ---------------------------------------------------------------------------
// conv_mid128: X [B,512,T] -> Y [B,512,T], K=3 SAME, no relu (encoder z).
// Tile 128 t x 128 o; per-thread 8 t x 8 o. grid (T/128, 512/128, B), block 256
// LDS reads per FMA halved vs 64-tile version (9 reads / 192 FMA).
// ---------------------------------------------------------------------------
__global__ __launch_bounds__(256)
void conv_mid128(const float* __restrict__ X, const float* __restrict__ Wt,
                 const float* __restrict__ bias, float* __restrict__ Y) {
    const int t0 = blockIdx.x * 128;
    const int o0 = blockIdx.y * 128;
    const int b  = blockIdx.z;
    __shared__ __align__(16) float Xs[16][132];   // t: -1 .. 128 (130 used)
    __shared__ __align__(16) float Ws[48][132];
    const int tid = threadIdx.x;
    const int tx = tid & 15, ty = tid >> 4;       // tx: 8 t each, ty: 8 o each
    float acc[8][8] = {};
    const float* Xb = X + (size_t)b * Hc * Tn;

    for (int c0 = 0; c0 < Hc; c0 += 16) {
        // stage X: 16 c x 130 t (scalar; halo of 1 each side)
        for (int i = tid; i < 16 * 130; i += 256) {
            int cc = i / 130, tt = i - cc * 130;
            int t = t0 + tt - 1;
            float v = 0.f;
            if (t >= 0 && t < Tn) v = Xb[(size_t)(c0 + cc) * Tn + t];
            Xs[cc][tt] = v;
        }
        // stage W: 48 x 128 as float4 (6144 floats = 1536 float4, 6 iters)
        #pragma unroll
        for (int it = 0; it < 6; ++it) {
            int i = tid + it * 256;
            int ck = i >> 5, o4 = i & 31;
            *(float4*)&Ws[ck][o4 * 4] =
                *(const float4*)&Wt[(size_t)(c0 * 3 + ck) * Hc + o0 + o4 * 4];
        }
        __syncthreads();
        #pragma unroll
        for (int cc = 0; cc < 16; ++cc) {
            float4 xa = *(const float4*)&Xs[cc][tx * 8];
            float4 xb4 = *(const float4*)&Xs[cc][tx * 8 + 4];
            float2 xc2 = *(const float2*)&Xs[cc][tx * 8 + 8];
            float xv[10] = {xa.x, xa.y, xa.z, xa.w, xb4.x, xb4.y, xb4.z, xb4.w,
                            xc2.x, xc2.y};
            #pragma unroll
            for (int k = 0; k < 3; ++k) {
                float4 wa = *(const float4*)&Ws[cc * 3 + k][ty * 8];
                float4 wb = *(const float4*)&Ws[cc * 3 + k][ty * 8 + 4];
                float wv[8] = {wa.x, wa.y, wa.z, wa.w, wb.x, wb.y, wb.z, wb.w};
                #pragma unroll
                for (int i8 = 0; i8 < 8; ++i8)
                    #pragma unroll
                    for (int j = 0; j < 8; ++j)
                        acc[i8][j] = fmaf(wv[i8], xv[k + j], acc[i8][j]);
            }
        }
        __syncthreads();
    }
    float* Yb = Y + (size_t)b * Hc * Tn;
    #pragma unroll
    for (int i8 = 0; i8 < 8; ++i8) {
        int o = o0 + ty * 8 + i8;
        float bv = bias[o];
        float4 r0, r1;
        r0.x = acc[i8][0] + bv; r0.y = acc[i8][1] + bv;
        r0.z = acc[i8][2] + bv; r0.w = acc[i8][3] + bv;
        r1.x = acc[i8][4] + bv; r1.y = acc[i8][5] + bv;
        r1.z = acc[i8][6] + bv; r1.w = acc[i8][7] + bv;
        float* yp = &Yb[(size_t)o * Tn + t0 + tx * 8];
        *(float4*)yp = r0;
        *(float4*)(yp + 4) = r1;
    }
}

// ---------------------------------------------------------------------------
// conv_dec2: X [B,512,T] -> recon [B,T,80]. Tile 64 t x 128 o (only 80 live).
// grid (T/64, 1, B), block 256
// ---------------------------------------------------------------------------
__global__ __launch_bounds__(256)
void conv_dec2(const float* __restrict__ X, const float* __restrict__ Wt,
               const float* __restrict__ bias, float* __restrict__ OUT) {
    const int t0 = blockIdx.x * 64;
    const int b  = blockIdx.z;
    __shared__ __align__(16) float Xs[16][72];
    __shared__ __align__(16) float Ws[48][132];
    const int tid = threadIdx.x;
    const int tx = tid & 15, ty = tid >> 4;
    float acc[8][4] = {};
    const float* Xb = X + (size_t)b * Hc * Tn;

    for (int c0 = 0; c0 < Hc; c0 += 16) {
        for (int i = tid; i < 16 * 66; i += 256) {
            int cc = i / 66, tt = i % 66;
            int t = t0 + tt - 1;
            float v = 0.f;
            if (t >= 0 && t < Tn) v = Xb[(size_t)(c0 + cc) * Tn + t];
            Xs[cc][tt] = v;
        }
        for (int i = tid; i < 48 * 128; i += 256) {
            int o = i & 127, ck = i >> 7;
            Ws[ck][o] = (o < INC) ? Wt[(size_t)(c0 * 3 + ck) * INC + o] : 0.f;
        }
        __syncthreads();
        #pragma unroll
        for (int cc = 0; cc < 16; ++cc) {
            float4 xa = *(const float4*)&Xs[cc][tx * 4];
            float2 xb2 = *(const float2*)&Xs[cc][tx * 4 + 4];
            float xv[6] = {xa.x, xa.y, xa.z, xa.w, xb2.x, xb2.y};
            #pragma unroll
            for (int k = 0; k < 3; ++k) {
                float4 wa = *(const float4*)&Ws[cc * 3 + k][ty * 8];
                float4 wb = *(const float4*)&Ws[cc * 3 + k][ty * 8 + 4];
                float wv[8] = {wa.x, wa.y, wa.z, wa.w, wb.x, wb.y, wb.z, wb.w};
                #pragma unroll
                for (int i8 = 0; i8 < 8; ++i8)
                    #pragma unroll
                    for (int j = 0; j < 4; ++j)
                        acc[i8][j] = fmaf(wv[i8], xv[k + j], acc[i8][j]);
            }
        }
        __syncthreads();
    }
    if (ty < 10) {
        float bv[8];
        #pragma unroll
        for (int i8 = 0; i8 < 8; ++i8) bv[i8] = bias[ty * 8 + i8];
        #pragma unroll
        for (int j = 0; j < 4; ++j) {
            int t = t0 + tx * 4 + j;
            float4 s0, s1;
            s0.x = acc[0][j] + bv[0]; s0.y = acc[1][j] + bv[1];
            s0.z = acc[2][j] + bv[2]; s0.w = acc[3][j] + bv[3];
            s1.x = acc[4][j] + bv[4]; s1.y = acc[5][j] + bv[5];
            s1.z = acc[6][j] + bv[6]; s1.w = acc[7][j] + bv[7];
            float* op = OUT + ((size_t)b * Tn + t) * INC + ty * 8;
            *(float4*)op = s0;
            *(float4*)(op + 4) = s1;
        }
    }
}

// ---------------------------------------------------------------------------
// vq_partial: per code-quarter partial argmin of CN[j] - 2 z.c_j.
// grid (T/64, B, 4), block 256. Per thread: 4 positions x 16 codes.
// ---------------------------------------------------------------------------
__global__ __launch_bounds__(256)
void vq_partial(const float* __restrict__ Z, const float* __restrict__ CBt,
                const float* __restrict__ CN, float* __restrict__ candv,
                int* __restrict__ candi) {
    const int t0 = blockIdx.x * 64;
    const int b  = blockIdx.y;
    const int jbase = blockIdx.z * 256;
    const int tid = threadIdx.x;
    const int tx = tid & 15, ty = tid >> 4;
    __shared__ __align__(16) float Zs[16][68];
    __shared__ __align__(16) float Cs[16][260];
    __shared__ float rv[64][17];
    __shared__ int   ri[64][17];

    float acc[16][4] = {};   // [code16][pos]
    const float* Zb = Z + (size_t)b * Dc * Tn + t0;

    for (int d0 = 0; d0 < Dc; d0 += 16) {
        for (int i = tid; i < 1024; i += 256) {
            int dd = i >> 6, tt = i & 63;
            Zs[dd][tt] = Zb[(size_t)(d0 + dd) * Tn + tt];
        }
        for (int i = tid; i < 1024; i += 256) {
            int dd = i >> 6, j4 = i & 63;
            *(float4*)&Cs[dd][j4 * 4] =
                *(const float4*)&CBt[(size_t)(d0 + dd) * NCODE + jbase + j4 * 4];
        }
        __syncthreads();
        #pragma unroll
        for (int dd = 0; dd < 16; ++dd) {
            float4 z = *(const float4*)&Zs[dd][tx * 4];
            float zp[4] = {z.x, z.y, z.z, z.w};
            #pragma unroll
            for (int s = 0; s < 4; ++s) {
                float4 c = *(const float4*)&Cs[dd][s * 64 + ty * 4];
                float cp[4] = {c.x, c.y, c.z, c.w};
                #pragma unroll
                for (int q = 0; q < 4; ++q)
                    #pragma unroll
                    for (int p = 0; p < 4; ++p)
                        acc[s * 4 + q][p] = fmaf(cp[q], zp[p], acc[s * 4 + q][p]);
            }
        }
        __syncthreads();
    }
    float bestv[4];
    int   besti[4];
    #pragma unroll
    for (int p = 0; p < 4; ++p) { bestv[p] = 1e30f; besti[p] = 0; }
    #pragma unroll
    for (int s = 0; s < 4; ++s)
        #pragma unroll
        for (int q = 0; q < 4; ++q) {
            int j = jbase + s * 64 + ty * 4 + q;
            float cnv = CN[j];
            #pragma unroll
            for (int p = 0; p < 4; ++p) {
                float dist = fmaf(-2.f, acc[s * 4 + q][p], cnv);
                if (dist < bestv[p] || (dist == bestv[p] && j < besti[p])) {
                    bestv[p] = dist; besti[p] = j;
                }
            }
        }
    #pragma unroll
    for (int p = 0; p < 4; ++p) {
        rv[tx * 4 + p][ty] = bestv[p];
        ri[tx * 4 + p][ty] = besti[p];
    }
    __syncthreads();
    if (tid < 64) {
        float bv = rv[tid][0];
        int   bi = ri[tid][0];
        #pragma unroll
        for (int y = 1; y < 16; ++y) {
            float v = rv[tid][y];
            int   i2 = ri[tid][y];
            if (v < bv || (v == bv && i2 < bi)) { bv = v; bi = i2; }
        }
        int n = b * Tn + t0 + tid;
        candv[(size_t)blockIdx.z * BT + n] = bv;
        candi[(size_t)blockIdx.z * BT + n] = bi;
    }
}

// ---------------------------------------------------------------------------
// vq_reduce: merge 4 candidates per position. grid (BT/256), block 256
// ---------------------------------------------------------------------------
__global__ __launch_bounds__(256)
void vq_reduce(const float* __restrict__ candv, const int* __restrict__ candi,
               int* __restrict__ idxI, float* __restrict__ idxf) {
    int n = blockIdx.x * 256 + threadIdx.x;
    float bv = candv[n];
    int   bi = candi[n];
    #pragma unroll
    for (int jq = 1; jq < 4; ++jq) {
        float v = candv[(size_t)jq * BT + n];
        int   i2 = candi[(size_t)jq * BT + n];
        if (v < bv || (v == bv && i2 < bi)) { bv = v; bi = i2; }
    }
    idxI[n] = bi;
    idxf[n] = (float)bi;
}

// ---------------------------------------------------------------------------
// gemm_g: G[j][kk*512+o] = sum_c CB[j][c] * dec_w1[o][c][kk].
// A from CBt ([c][j], coalesced), B from wt3 ([c*3+kk][o], coalesced).
// grid (NCODE/64, 12) where y: kk = y>>2, o0 = (y&3)*128. block 256, 4j x 8o.
// ---------------------------------------------------------------------------
__global__ __launch_bounds__(256)
void gemm_g(const float* __restrict__ CBt, const float* __restrict__ Wt,
            float* __restrict__ G) {
    const int j0 = blockIdx.x * 64;
    const int kk = blockIdx.y >> 2;
    const int o0 = (blockIdx.y & 3) * 128;
    __shared__ __align__(16) float As[16][68];    // [c][j]
    __shared__ __align__(16) float Bs[16][132];   // [c][o]
    const int tid = threadIdx.x;
    const int tx = tid & 15, ty = tid >> 4;
    float acc[4][8] = {};   // [j][o]

    for (int c0 = 0; c0 < Dc; c0 += 16) {
        {   // As: 1024 floats = 256 float4, 1 iter
            int cc = tid >> 4, j4 = tid & 15;
            *(float4*)&As[cc][j4 * 4] =
                *(const float4*)&CBt[(size_t)(c0 + cc) * NCODE + j0 + j4 * 4];
        }
        #pragma unroll
        for (int it = 0; it < 2; ++it) {   // Bs: 2048 floats = 512 float4
            int i = tid + it * 256;
            int cc = i >> 5, o4 = i & 31;
            *(float4*)&Bs[cc][o4 * 4] =
                *(const float4*)&Wt[(size_t)((c0 + cc) * 3 + kk) * Hc + o0 + o4 * 4];
        }
        __syncthreads();
        #pragma unroll
        for (int cc = 0; cc < 16; ++cc) {
            float4 a = *(const float4*)&As[cc][tx * 4];
            float av[4] = {a.x, a.y, a.z, a.w};
            float4 b0 = *(const float4*)&Bs[cc][ty * 8];
            float4 b1 = *(const float4*)&Bs[cc][ty * 8 + 4];
            float bv[8] = {b0.x, b0.y, b0.z, b0.w, b1.x, b1.y, b1.z, b1.w};
            #pragma unroll
            for (int jj = 0; jj < 4; ++jj)
                #pragma unroll
                for (int oo = 0; oo < 8; ++oo)
                    acc[jj][oo] = fmaf(av[jj], bv[oo], acc[jj][oo]);
        }
        __syncthreads();
    }
    #pragma unroll
    for (int jj = 0; jj < 4; ++jj) {
        int j = j0 + tx * 4 + jj;
        float* gp = G + (size_t)j * 1536 + kk * 512 + o0 + ty * 8;
        *(float4*)gp = *(float4*)&acc[jj][0];
        *(float4*)(gp + 4) = *(float4*)&acc[jj][4];
    }
}

// ---------------------------------------------------------------------------
// dec_y3: y3[b][o][t] = relu(b1[o] + sum_kk G[idx[b][t+kk-1]][kk*512+o]).
// Replaces decoder conv1 (input is codebook rows -> precomputed G).
// grid (T/64, 4 o-tiles, B), block 256. Reads coalesced over o; writes staged
// through LDS for coalescing over t.
// ---------------------------------------------------------------------------
__global__ __launch_bounds__(256)
void dec_y3(const int* __restrict__ idx, const float* __restrict__ G,
            const float* __restrict__ bias, float* __restrict__ Y) {
    const int t0 = blockIdx.x * 64;
    const int o0 = blockIdx.y * 128;
    const int b  = blockIdx.z;
    const int tid = threadIdx.x;
    __shared__ int sidx[66];
    __shared__ __align__(16) float Ys[128][68];

    if (tid < 66) {
        int t = t0 + tid - 1;
        sidx[tid] = (t >= 0 && t < Tn) ? idx[b * Tn + t] : -1;
    }
    __syncthreads();

    const int o = tid & 127;        // 0..127
    const int half = tid >> 7;      // 0..1 (wave-uniform)
    float acc[32] = {};
    #pragma unroll
    for (int kk = 0; kk < 3; ++kk) {
        const float* Gk = G + (size_t)kk * 512 + o0 + o;
        #pragma unroll
        for (int k = 0; k < 32; ++k) {
            int j = sidx[half + 2 * k + kk];   // wave-uniform
            if (j >= 0) acc[k] += Gk[(size_t)j * 1536];
        }
    }
    float bv = bias[o0 + o];
    #pragma unroll
    for (int k = 0; k < 32; ++k)
        Ys[o][half + 2 * k] = fmaxf(acc[k] + bv, 0.f);
    __syncthreads();

    float* Yb = Y + (size_t)b * Hc * Tn + t0;
    #pragma unroll
    for (int it = 0; it < 8; ++it) {
        int i = tid + it * 256;
        int t4 = i & 15, oo = i >> 4;
        *(float4*)&Yb[(size_t)(o0 + oo) * Tn + t4 * 4] =
            *(const float4*)&Ys[oo][t4 * 4];
    }
}

// ---------------------------------------------------------------------------
extern "C" void kernel_launch(void* const* d_in, const int* in_sizes, int n_in,
                              void* d_out, int out_size, void* d_ws, size_t ws_size,
                              hipStream_t stream) {
    const float* mels    = (const float*)d_in[0];
    const float* enc_w1  = (const float*)d_in[1];
    const float* enc_b1  = (const float*)d_in[2];
    const float* enc_w2  = (const float*)d_in[3];
    const float* enc_b2  = (const float*)d_in[4];
    const float* codebook= (const float*)d_in[5];
    const float* dec_w1  = (const float*)d_in[6];
    const float* dec_b1  = (const float*)d_in[7];
    const float* dec_w2  = (const float*)d_in[8];
    const float* dec_b2  = (const float*)d_in[9];

    float* out = (float*)d_out;
    float* recon = out;                 // [B,T,80]
    float* idxf  = out + RECON_N;       // [B,T] as float

    const size_t ACT = (size_t)Bsz * Hc * Tn;   // 16,777,216 floats (64 MB)
    float* bufA = (float*)d_ws;                 // y1, later y3
    float* bufB = bufA + ACT;                   // z
    int*   idxI = (int*)(bufB + ACT);           // [B*T]
    float* cn   = (float*)(idxI + BT);          // [NCODE]
    float* cbt  = cn + NCODE;                   // [512*1024]
    float* wt1  = cbt + (size_t)Dc * NCODE;     // enc_w1t: 80*3*512
    float* wt2  = wt1 + (size_t)INC * 3 * Hc;   // enc_w2t: 512*3*512
    float* wt3  = wt2 + (size_t)Hc * 3 * Dc;    // dec_w1t: 512*3*512
    float* wt4  = wt3 + (size_t)Dc * 3 * Hc;    // dec_w2t: 512*3*80
    float* candv = wt4 + (size_t)Hc * 3 * INC;  // [4*BT]
    int*   candi = (int*)(candv + 4 * BT);      // [4*BT]
    float* G    = (float*)(candi + 4 * BT);     // [1024*1536]

    dim3 blk(256);
    // prep: norms + transposes (cheap, every call — graph-capture safe)
    code_norms<<<dim3(NCODE), dim3(64), 0, stream>>>(codebook, cn);
    cb_transpose<<<dim3(NCODE / 64, Dc / 64), blk, 0, stream>>>(codebook, cbt);
    wt_transpose<<<dim3(Hc / 64, INC / 16), blk, 0, stream>>>(enc_w1, wt1, INC, Hc);
    wt_transpose<<<dim3(Dc / 64, Hc / 16), blk, 0, stream>>>(enc_w2, wt2, Hc, Dc);
    wt_transpose<<<dim3(Hc / 64, Dc / 16), blk, 0, stream>>>(dec_w1, wt3, Dc, Hc);
    wt_transpose<<<dim3(2, Hc / 16), blk, 0, stream>>>(dec_w2, wt4, Hc, INC);
    // decoder conv1 folded matrix (independent of activations)
    gemm_g<<<dim3(NCODE / 64, 12), blk, 0, stream>>>(cbt, wt3, G);
    // encoder
    conv_enc1<<<dim3(Tn / 64, Hc / 128, Bsz), blk, 0, stream>>>(mels, wt1, enc_b1, bufA);
    conv_mid128<<<dim3(Tn / 128, Dc / 128, Bsz), blk, 0, stream>>>(bufA, wt2, enc_b2, bufB);
    // vector quantization
    vq_partial<<<dim3(Tn / 64, Bsz, 4), blk, 0, stream>>>(bufB, cbt, cn, candv, candi);
    vq_reduce<<<dim3(BT / 256), blk, 0, stream>>>(candv, candi, idxI, idxf);
    // decoder: conv1 via gather of G rows, then conv2
    dec_y3<<<dim3(Tn / 64, 4, Bsz), blk, 0, stream>>>(idxI, G, dec_b1, bufA);
    conv_dec2<<<dim3(Tn / 64, 1, Bsz), blk, 0, stream>>>(bufA, wt4, dec_b2, recon);
}

// Round 4
// 1736.298 us; speedup vs baseline: 1.8369x; 1.0355x over previous
//
#include <hip/hip_runtime.h>
#include <hip/hip_bf16.h>

// Problem constants
#define Bsz   16
#define Tn    2048
#define INC   80
#define Hc    512
#define Dc    512
#define NCODE 1024
#define BT    (Bsz * Tn)           // 32768
#define RECON_N (Bsz * Tn * INC)   // 2,621,440

// ---------------------------------------------------------------------------
// code_norms: CN[j] = sum_d CB[j][d]^2
// ---------------------------------------------------------------------------
__global__ __launch_bounds__(64)
void code_norms(const float* __restrict__ CB, float* __restrict__ CN) {
    int j = blockIdx.x;
    int lane = threadIdx.x;
    const float4* row = (const float4*)(CB + (size_t)j * Dc);
    float s = 0.f;
    #pragma unroll
    for (int i = 0; i < 2; ++i) {
        float4 v = row[lane + i * 64];
        s = fmaf(v.x, v.x, s);
        s = fmaf(v.y, v.y, s);
        s = fmaf(v.z, v.z, s);
        s = fmaf(v.w, v.w, s);
    }
    #pragma unroll
    for (int off = 32; off > 0; off >>= 1) s += __shfl_down(s, off, 64);
    if (lane == 0) CN[j] = s;
}

// ---------------------------------------------------------------------------
// cb_transpose: CBt[d][j] = CB[j][d].  grid (NCODE/64, Dc/64), block 256
// ---------------------------------------------------------------------------
__global__ __launch_bounds__(256)
void cb_transpose(const float* __restrict__ CB, float* __restrict__ CBt) {
    const int j0 = blockIdx.x * 64;
    const int d0 = blockIdx.y * 64;
    __shared__ float ts[64][65];
    const int tid = threadIdx.x;
    for (int i = tid; i < 4096; i += 256) {
        int r = i >> 6, c = i & 63;
        ts[r][c] = CB[(size_t)(j0 + r) * Dc + d0 + c];
    }
    __syncthreads();
    for (int i = tid; i < 4096; i += 256) {
        int r = i >> 6, c = i & 63;
        CBt[(size_t)(d0 + r) * NCODE + j0 + c] = ts[c][r];
    }
}

// ---------------------------------------------------------------------------
// wt_transpose: Wt[(c*3+k)*Cout + o] = W[(o*Cin + c)*3 + k]
// grid (ceil(Cout/64), Cin/16), block 256
// ---------------------------------------------------------------------------
__global__ __launch_bounds__(256)
void wt_transpose(const float* __restrict__ W, float* __restrict__ Wt,
                  int Cin, int Cout) {
    const int o0 = blockIdx.x * 64;
    const int c0 = blockIdx.y * 16;
    __shared__ float ts[48][65];
    const int tid = threadIdx.x;
    for (int i = tid; i < 64 * 48; i += 256) {
        int o = i / 48, ck = i % 48;
        int oo = o0 + o;
        float v = 0.f;
        if (oo < Cout) v = W[(size_t)oo * Cin * 3 + c0 * 3 + ck];
        ts[ck][o] = v;
    }
    __syncthreads();
    for (int i = tid; i < 48 * 64; i += 256) {
        int o = i & 63, ck = i >> 6;
        int oo = o0 + o;
        if (oo < Cout) Wt[(size_t)(c0 * 3 + ck) * Cout + oo] = ts[ck][o];
    }
}

// ---------------------------------------------------------------------------
// conv_enc1: mels [B,T,80] -> Y [B,512,T], K=3 SAME, ReLU at store.
// Tile 64 t x 128 o; per-thread 4 t x 8 o (o split {ty*4, 64+ty*4} for
// conflict-free b128 LDS reads). grid (T/64, 512/128, B), block 256
// ---------------------------------------------------------------------------
__global__ __launch_bounds__(256)
void conv_enc1(const float* __restrict__ X, const float* __restrict__ Wt,
               const float* __restrict__ bias, float* __restrict__ Y) {
    const int t0 = blockIdx.x * 64;
    const int o0 = blockIdx.y * 128;
    const int b  = blockIdx.z;
    __shared__ __align__(16) float Xs[16][72];
    __shared__ __align__(16) float Ws[48][132];
    const int tid = threadIdx.x;
    const int tx = tid & 15, ty = tid >> 4;
    float acc[8][4] = {};   // [o8: og*4+oi][t4]

    for (int c0 = 0; c0 < INC; c0 += 16) {
        for (int i = tid; i < 16 * 66; i += 256) {
            int cc = i / 66, tt = i % 66;
            int t = t0 + tt - 1;
            float v = 0.f;
            if (t >= 0 && t < Tn) v = X[((size_t)b * Tn + t) * INC + c0 + cc];
            Xs[cc][tt] = v;
        }
        for (int i = tid; i < 48 * 128; i += 256) {
            int o = i & 127, ck = i >> 7;
            Ws[ck][o] = Wt[(size_t)(c0 * 3 + ck) * Hc + o0 + o];
        }
        __syncthreads();
        #pragma unroll
        for (int cc = 0; cc < 16; ++cc) {
            float4 xa = *(const float4*)&Xs[cc][tx * 4];
            float2 xb2 = *(const float2*)&Xs[cc][tx * 4 + 4];
            float xv[6] = {xa.x, xa.y, xa.z, xa.w, xb2.x, xb2.y};
            #pragma unroll
            for (int k = 0; k < 3; ++k) {
                float4 wa = *(const float4*)&Ws[cc * 3 + k][ty * 4];
                float4 wb = *(const float4*)&Ws[cc * 3 + k][64 + ty * 4];
                float wv[8] = {wa.x, wa.y, wa.z, wa.w, wb.x, wb.y, wb.z, wb.w};
                #pragma unroll
                for (int i8 = 0; i8 < 8; ++i8)
                    #pragma unroll
                    for (int j = 0; j < 4; ++j)
                        acc[i8][j] = fmaf(wv[i8], xv[k + j], acc[i8][j]);
            }
        }
        __syncthreads();
    }
    float* Yb = Y + (size_t)b * Hc * Tn;
    #pragma unroll
    for (int og = 0; og < 2; ++og)
        #pragma unroll
        for (int oi = 0; oi < 4; ++oi) {
            int o = o0 + og * 64 + ty * 4 + oi;
            float bv = bias[o];
            const int i8 = og * 4 + oi;
            float4 r;
            r.x = fmaxf(acc[i8][0] + bv, 0.f);
            r.y = fmaxf(acc[i8][1] + bv, 0.f);
            r.z = fmaxf(acc[i8][2] + bv, 0.f);
            r.w = fmaxf(acc[i8][3] + bv, 0.f);
            *(float4*)&Yb[(size_t)o * Tn + t0 + tx * 4] = r;
        }
}

// ---------------------------------------------------------------------------
// conv_mid256: X [B,512,T] -> Y [B,512,T], K=3 SAME, no relu (encoder z).
// Tile 256 t x 128 o; per-thread 16 t x 8 o in conflict-free groups of 4:
// t = tx*4 + g*64 (g=0..3), o = ty*4 + og*64 (og=0..1).
// Per cc-iter: 96B X + 96B W LDS for 384 FMAs = 2.0 FMA/byte -> VALU-bound.
// grid (T/256, 512/128, B) = 512 blocks = 2 blocks/CU.
// ---------------------------------------------------------------------------
__global__ __launch_bounds__(256, 2)
void conv_mid256(const float* __restrict__ X, const float* __restrict__ Wt,
                 const float* __restrict__ bias, float* __restrict__ Y) {
    const int t0 = blockIdx.x * 256;
    const int o0 = blockIdx.y * 128;
    const int b  = blockIdx.z;
    __shared__ __align__(16) float Xs[16][260];   // t: -1 .. 256 (258 used)
    __shared__ __align__(16) float Ws[48][132];
    const int tid = threadIdx.x;
    const int tx = tid & 15, ty = tid >> 4;
    float acc[16][8] = {};   // [t: g*4+j][o: og*4+oi]
    const float* Xb = X + (size_t)b * Hc * Tn;

    for (int c0 = 0; c0 < Hc; c0 += 16) {
        // stage X: 16 c x 258 t (halo of 1 each side), coalesced over t
        for (int i = tid; i < 16 * 258; i += 256) {
            int cc = i / 258, tt = i - cc * 258;
            int t = t0 + tt - 1;
            float v = 0.f;
            if (t >= 0 && t < Tn) v = Xb[(size_t)(c0 + cc) * Tn + t];
            Xs[cc][tt] = v;
        }
        // stage W: 48 x 128 as float4
        #pragma unroll
        for (int it = 0; it < 6; ++it) {
            int i = tid + it * 256;
            int ck = i >> 5, o4 = i & 31;
            *(float4*)&Ws[ck][o4 * 4] =
                *(const float4*)&Wt[(size_t)(c0 * 3 + ck) * Hc + o0 + o4 * 4];
        }
        __syncthreads();
        #pragma unroll
        for (int cc = 0; cc < 16; ++cc) {
            float xv[4][6];
            #pragma unroll
            for (int g = 0; g < 4; ++g) {
                float4 xa = *(const float4*)&Xs[cc][tx * 4 + g * 64];
                float2 xb2 = *(const float2*)&Xs[cc][tx * 4 + g * 64 + 4];
                xv[g][0] = xa.x; xv[g][1] = xa.y; xv[g][2] = xa.z;
                xv[g][3] = xa.w; xv[g][4] = xb2.x; xv[g][5] = xb2.y;
            }
            #pragma unroll
            for (int k = 0; k < 3; ++k) {
                float4 wa = *(const float4*)&Ws[cc * 3 + k][ty * 4];
                float4 wb = *(const float4*)&Ws[cc * 3 + k][64 + ty * 4];
                float wv[8] = {wa.x, wa.y, wa.z, wa.w, wb.x, wb.y, wb.z, wb.w};
                #pragma unroll
                for (int g = 0; g < 4; ++g)
                    #pragma unroll
                    for (int j = 0; j < 4; ++j) {
                        float xx = xv[g][k + j];
                        #pragma unroll
                        for (int o8 = 0; o8 < 8; ++o8)
                            acc[g * 4 + j][o8] = fmaf(wv[o8], xx, acc[g * 4 + j][o8]);
                    }
            }
        }
        __syncthreads();
    }
    float* Yb = Y + (size_t)b * Hc * Tn;
    #pragma unroll
    for (int og = 0; og < 2; ++og)
        #pragma unroll
        for (int oi = 0; oi < 4; ++oi) {
            int o = o0 + og * 64 + ty * 4 + oi;
            float bv = bias[o];
            const int o8 = og * 4 + oi;
            #pragma unroll
            for (int g = 0; g < 4; ++g) {
                float4 r;
                r.x = acc[g * 4 + 0][o8] + bv;
                r.y = acc[g * 4 + 1][o8] + bv;
                r.z = acc[g * 4 + 2][o8] + bv;
                r.w = acc[g * 4 + 3][o8] + bv;
                *(float4*)&Yb[(size_t)o * Tn + t0 + g * 64 + tx * 4] = r;
            }
        }
}

// ---------------------------------------------------------------------------
// conv_dec2: X [B,512,T] -> recon [B,T,80]. Tile 64 t x 128 o (80 live),
// o split {ty*4, 64+ty*4}. grid (T/64, 1, B), block 256
// ---------------------------------------------------------------------------
__global__ __launch_bounds__(256)
void conv_dec2(const float* __restrict__ X, const float* __restrict__ Wt,
               const float* __restrict__ bias, float* __restrict__ OUT) {
    const int t0 = blockIdx.x * 64;
    const int b  = blockIdx.z;
    __shared__ __align__(16) float Xs[16][72];
    __shared__ __align__(16) float Ws[48][132];
    const int tid = threadIdx.x;
    const int tx = tid & 15, ty = tid >> 4;
    float acc[8][4] = {};   // [o8: og*4+oi][t4]
    const float* Xb = X + (size_t)b * Hc * Tn;

    for (int c0 = 0; c0 < Hc; c0 += 16) {
        for (int i = tid; i < 16 * 66; i += 256) {
            int cc = i / 66, tt = i % 66;
            int t = t0 + tt - 1;
            float v = 0.f;
            if (t >= 0 && t < Tn) v = Xb[(size_t)(c0 + cc) * Tn + t];
            Xs[cc][tt] = v;
        }
        for (int i = tid; i < 48 * 128; i += 256) {
            int o = i & 127, ck = i >> 7;
            Ws[ck][o] = (o < INC) ? Wt[(size_t)(c0 * 3 + ck) * INC + o] : 0.f;
        }
        __syncthreads();
        #pragma unroll
        for (int cc = 0; cc < 16; ++cc) {
            float4 xa = *(const float4*)&Xs[cc][tx * 4];
            float2 xb2 = *(const float2*)&Xs[cc][tx * 4 + 4];
            float xv[6] = {xa.x, xa.y, xa.z, xa.w, xb2.x, xb2.y};
            #pragma unroll
            for (int k = 0; k < 3; ++k) {
                float4 wa = *(const float4*)&Ws[cc * 3 + k][ty * 4];
                float4 wb = *(const float4*)&Ws[cc * 3 + k][64 + ty * 4];
                float wv[8] = {wa.x, wa.y, wa.z, wa.w, wb.x, wb.y, wb.z, wb.w};
                #pragma unroll
                for (int i8 = 0; i8 < 8; ++i8)
                    #pragma unroll
                    for (int j = 0; j < 4; ++j)
                        acc[i8][j] = fmaf(wv[i8], xv[k + j], acc[i8][j]);
            }
        }
        __syncthreads();
    }
    // group0: o = ty*4 (0..63, all live). group1: o = 64+ty*4, live iff ty<4.
    {
        float bv[4];
        #pragma unroll
        for (int oi = 0; oi < 4; ++oi) bv[oi] = bias[ty * 4 + oi];
        #pragma unroll
        for (int j = 0; j < 4; ++j) {
            int t = t0 + tx * 4 + j;
            float4 s;
            s.x = acc[0][j] + bv[0];
            s.y = acc[1][j] + bv[1];
            s.z = acc[2][j] + bv[2];
            s.w = acc[3][j] + bv[3];
            *(float4*)(OUT + ((size_t)b * Tn + t) * INC + ty * 4) = s;
        }
    }
    if (ty < 4) {
        float bv[4];
        #pragma unroll
        for (int oi = 0; oi < 4; ++oi) bv[oi] = bias[64 + ty * 4 + oi];
        #pragma unroll
        for (int j = 0; j < 4; ++j) {
            int t = t0 + tx * 4 + j;
            float4 s;
            s.x = acc[4][j] + bv[0];
            s.y = acc[5][j] + bv[1];
            s.z = acc[6][j] + bv[2];
            s.w = acc[7][j] + bv[3];
            *(float4*)(OUT + ((size_t)b * Tn + t) * INC + 64 + ty * 4) = s;
        }
    }
}

// ---------------------------------------------------------------------------
// vq_partial: per code-quarter partial argmin of CN[j] - 2 z.c_j.
// grid (T/64, B, 4), block 256. Per thread: 4 positions x 16 codes.
// ---------------------------------------------------------------------------
__global__ __launch_bounds__(256)
void vq_partial(const float* __restrict__ Z, const float* __restrict__ CBt,
                const float* __restrict__ CN, float* __restrict__ candv,
                int* __restrict__ candi) {
    const int t0 = blockIdx.x * 64;
    const int b  = blockIdx.y;
    const int jbase = blockIdx.z * 256;
    const int tid = threadIdx.x;
    const int tx = tid & 15, ty = tid >> 4;
    __shared__ __align__(16) float Zs[16][68];
    __shared__ __align__(16) float Cs[16][260];
    __shared__ float rv[64][17];
    __shared__ int   ri[64][17];

    float acc[16][4] = {};   // [code16][pos]
    const float* Zb = Z + (size_t)b * Dc * Tn + t0;

    for (int d0 = 0; d0 < Dc; d0 += 16) {
        for (int i = tid; i < 1024; i += 256) {
            int dd = i >> 6, tt = i & 63;
            Zs[dd][tt] = Zb[(size_t)(d0 + dd) * Tn + tt];
        }
        for (int i = tid; i < 1024; i += 256) {
            int dd = i >> 6, j4 = i & 63;
            *(float4*)&Cs[dd][j4 * 4] =
                *(const float4*)&CBt[(size_t)(d0 + dd) * NCODE + jbase + j4 * 4];
        }
        __syncthreads();
        #pragma unroll
        for (int dd = 0; dd < 16; ++dd) {
            float4 z = *(const float4*)&Zs[dd][tx * 4];
            float zp[4] = {z.x, z.y, z.z, z.w};
            #pragma unroll
            for (int s = 0; s < 4; ++s) {
                float4 c = *(const float4*)&Cs[dd][s * 64 + ty * 4];
                float cp[4] = {c.x, c.y, c.z, c.w};
                #pragma unroll
                for (int q = 0; q < 4; ++q)
                    #pragma unroll
                    for (int p = 0; p < 4; ++p)
                        acc[s * 4 + q][p] = fmaf(cp[q], zp[p], acc[s * 4 + q][p]);
            }
        }
        __syncthreads();
    }
    float bestv[4];
    int   besti[4];
    #pragma unroll
    for (int p = 0; p < 4; ++p) { bestv[p] = 1e30f; besti[p] = 0; }
    #pragma unroll
    for (int s = 0; s < 4; ++s)
        #pragma unroll
        for (int q = 0; q < 4; ++q) {
            int j = jbase + s * 64 + ty * 4 + q;
            float cnv = CN[j];
            #pragma unroll
            for (int p = 0; p < 4; ++p) {
                float dist = fmaf(-2.f, acc[s * 4 + q][p], cnv);
                if (dist < bestv[p] || (dist == bestv[p] && j < besti[p])) {
                    bestv[p] = dist; besti[p] = j;
                }
            }
        }
    #pragma unroll
    for (int p = 0; p < 4; ++p) {
        rv[tx * 4 + p][ty] = bestv[p];
        ri[tx * 4 + p][ty] = besti[p];
    }
    __syncthreads();
    if (tid < 64) {
        float bv = rv[tid][0];
        int   bi = ri[tid][0];
        #pragma unroll
        for (int y = 1; y < 16; ++y) {
            float v = rv[tid][y];
            int   i2 = ri[tid][y];
            if (v < bv || (v == bv && i2 < bi)) { bv = v; bi = i2; }
        }
        int n = b * Tn + t0 + tid;
        candv[(size_t)blockIdx.z * BT + n] = bv;
        candi[(size_t)blockIdx.z * BT + n] = bi;
    }
}

// ---------------------------------------------------------------------------
// vq_reduce: merge 4 candidates per position. grid (BT/256), block 256
// ---------------------------------------------------------------------------
__global__ __launch_bounds__(256)
void vq_reduce(const float* __restrict__ candv, const int* __restrict__ candi,
               int* __restrict__ idxI, float* __restrict__ idxf) {
    int n = blockIdx.x * 256 + threadIdx.x;
    float bv = candv[n];
    int   bi = candi[n];
    #pragma unroll
    for (int jq = 1; jq < 4; ++jq) {
        float v = candv[(size_t)jq * BT + n];
        int   i2 = candi[(size_t)jq * BT + n];
        if (v < bv || (v == bv && i2 < bi)) { bv = v; bi = i2; }
    }
    idxI[n] = bi;
    idxf[n] = (float)bi;
}

// ---------------------------------------------------------------------------
// gemm_g: G[j][kk*512+o] = sum_c CB[j][c] * dec_w1[o][c][kk].
// grid (NCODE/64, 12): kk = y>>2, o0 = (y&3)*128. block 256, 4j x 8o.
// ---------------------------------------------------------------------------
__global__ __launch_bounds__(256)
void gemm_g(const float* __restrict__ CBt, const float* __restrict__ Wt,
            float* __restrict__ G) {
    const int j0 = blockIdx.x * 64;
    const int kk = blockIdx.y >> 2;
    const int o0 = (blockIdx.y & 3) * 128;
    __shared__ __align__(16) float As[16][68];    // [c][j]
    __shared__ __align__(16) float Bs[16][132];   // [c][o]
    const int tid = threadIdx.x;
    const int tx = tid & 15, ty = tid >> 4;
    float acc[4][8] = {};   // [j][o]

    for (int c0 = 0; c0 < Dc; c0 += 16) {
        {
            int cc = tid >> 4, j4 = tid & 15;
            *(float4*)&As[cc][j4 * 4] =
                *(const float4*)&CBt[(size_t)(c0 + cc) * NCODE + j0 + j4 * 4];
        }
        #pragma unroll
        for (int it = 0; it < 2; ++it) {
            int i = tid + it * 256;
            int cc = i >> 5, o4 = i & 31;
            *(float4*)&Bs[cc][o4 * 4] =
                *(const float4*)&Wt[(size_t)((c0 + cc) * 3 + kk) * Hc + o0 + o4 * 4];
        }
        __syncthreads();
        #pragma unroll
        for (int cc = 0; cc < 16; ++cc) {
            float4 a = *(const float4*)&As[cc][tx * 4];
            float av[4] = {a.x, a.y, a.z, a.w};
            float4 b0 = *(const float4*)&Bs[cc][ty * 4];
            float4 b1 = *(const float4*)&Bs[cc][64 + ty * 4];
            float bv[8] = {b0.x, b0.y, b0.z, b0.w, b1.x, b1.y, b1.z, b1.w};
            #pragma unroll
            for (int jj = 0; jj < 4; ++jj)
                #pragma unroll
                for (int oo = 0; oo < 8; ++oo)
                    acc[jj][oo] = fmaf(av[jj], bv[oo], acc[jj][oo]);
        }
        __syncthreads();
    }
    #pragma unroll
    for (int jj = 0; jj < 4; ++jj) {
        int j = j0 + tx * 4 + jj;
        float* gp = G + (size_t)j * 1536 + kk * 512 + o0;
        *(float4*)(gp + ty * 4) = *(float4*)&acc[jj][0];
        *(float4*)(gp + 64 + ty * 4) = *(float4*)&acc[jj][4];
    }
}

// ---------------------------------------------------------------------------
// dec_y3: y3[b][o][t] = relu(b1[o] + sum_kk G[idx[b][t+kk-1]][kk*512+o]).
// grid (T/64, 4 o-tiles, B), block 256.
// ---------------------------------------------------------------------------
__global__ __launch_bounds__(256)
void dec_y3(const int* __restrict__ idx, const float* __restrict__ G,
            const float* __restrict__ bias, float* __restrict__ Y) {
    const int t0 = blockIdx.x * 64;
    const int o0 = blockIdx.y * 128;
    const int b  = blockIdx.z;
    const int tid = threadIdx.x;
    __shared__ int sidx[66];
    __shared__ __align__(16) float Ys[128][68];

    if (tid < 66) {
        int t = t0 + tid - 1;
        sidx[tid] = (t >= 0 && t < Tn) ? idx[b * Tn + t] : -1;
    }
    __syncthreads();

    const int o = tid & 127;
    const int half = tid >> 7;
    float acc[32] = {};
    #pragma unroll
    for (int kk = 0; kk < 3; ++kk) {
        const float* Gk = G + (size_t)kk * 512 + o0 + o;
        #pragma unroll
        for (int k = 0; k < 32; ++k) {
            int j = sidx[half + 2 * k + kk];
            if (j >= 0) acc[k] += Gk[(size_t)j * 1536];
        }
    }
    float bv = bias[o0 + o];
    #pragma unroll
    for (int k = 0; k < 32; ++k)
        Ys[o][half + 2 * k] = fmaxf(acc[k] + bv, 0.f);
    __syncthreads();

    float* Yb = Y + (size_t)b * Hc * Tn + t0;
    #pragma unroll
    for (int it = 0; it < 8; ++it) {
        int i = tid + it * 256;
        int t4 = i & 15, oo = i >> 4;
        *(float4*)&Yb[(size_t)(o0 + oo) * Tn + t4 * 4] =
            *(const float4*)&Ys[oo][t4 * 4];
    }
}

// ---------------------------------------------------------------------------
extern "C" void kernel_launch(void* const* d_in, const int* in_sizes, int n_in,
                              void* d_out, int out_size, void* d_ws, size_t ws_size,
                              hipStream_t stream) {
    const float* mels    = (const float*)d_in[0];
    const float* enc_w1  = (const float*)d_in[1];
    const float* enc_b1  = (const float*)d_in[2];
    const float* enc_w2  = (const float*)d_in[3];
    const float* enc_b2  = (const float*)d_in[4];
    const float* codebook= (const float*)d_in[5];
    const float* dec_w1  = (const float*)d_in[6];
    const float* dec_b1  = (const float*)d_in[7];
    const float* dec_w2  = (const float*)d_in[8];
    const float* dec_b2  = (const float*)d_in[9];

    float* out = (float*)d_out;
    float* recon = out;                 // [B,T,80]
    float* idxf  = out + RECON_N;       // [B,T] as float

    const size_t ACT = (size_t)Bsz * Hc * Tn;   // 16,777,216 floats (64 MB)
    float* bufA = (float*)d_ws;                 // y1, later y3
    float* bufB = bufA + ACT;                   // z
    int*   idxI = (int*)(bufB + ACT);           // [B*T]
    float* cn   = (float*)(idxI + BT);          // [NCODE]
    float* cbt  = cn + NCODE;                   // [512*1024]
    float* wt1  = cbt + (size_t)Dc * NCODE;     // enc_w1t: 80*3*512
    float* wt2  = wt1 + (size_t)INC * 3 * Hc;   // enc_w2t: 512*3*512
    float* wt3  = wt2 + (size_t)Hc * 3 * Dc;    // dec_w1t: 512*3*512
    float* wt4  = wt3 + (size_t)Dc * 3 * Hc;    // dec_w2t: 512*3*80
    float* candv = wt4 + (size_t)Hc * 3 * INC;  // [4*BT]
    int*   candi = (int*)(candv + 4 * BT);      // [4*BT]
    float* G    = (float*)(candi + 4 * BT);     // [1024*1536]

    dim3 blk(256);
    // prep: norms + transposes (cheap, every call — graph-capture safe)
    code_norms<<<dim3(NCODE), dim3(64), 0, stream>>>(codebook, cn);
    cb_transpose<<<dim3(NCODE / 64, Dc / 64), blk, 0, stream>>>(codebook, cbt);
    wt_transpose<<<dim3(Hc / 64, INC / 16), blk, 0, stream>>>(enc_w1, wt1, INC, Hc);
    wt_transpose<<<dim3(Dc / 64, Hc / 16), blk, 0, stream>>>(enc_w2, wt2, Hc, Dc);
    wt_transpose<<<dim3(Hc / 64, Dc / 16), blk, 0, stream>>>(dec_w1, wt3, Dc, Hc);
    wt_transpose<<<dim3(2, Hc / 16), blk, 0, stream>>>(dec_w2, wt4, Hc, INC);
    // decoder conv1 folded matrix (independent of activations)
    gemm_g<<<dim3(NCODE / 64, 12), blk, 0, stream>>>(cbt, wt3, G);
    // encoder
    conv_enc1<<<dim3(Tn / 64, Hc / 128, Bsz), blk, 0, stream>>>(mels, wt1, enc_b1, bufA);
    conv_mid256<<<dim3(Tn / 256, Dc / 128, Bsz), blk, 0, stream>>>(bufA, wt2, enc_b2, bufB);
    // vector quantization
    vq_partial<<<dim3(Tn / 64, Bsz, 4), blk, 0, stream>>>(bufB, cbt, cn, candv, candi);
    vq_reduce<<<dim3(BT / 256), blk, 0, stream>>>(candv, candi, idxI, idxf);
    // decoder: conv1 via gather of G rows, then conv2
    dec_y3<<<dim3(Tn / 64, 4, Bsz), blk, 0, stream>>>(idxI, G, dec_b1, bufA);
    conv_dec2<<<dim3(Tn / 64, 1, Bsz), blk, 0, stream>>>(bufA, wt4, dec_b2, recon);
}

// Round 5
// 1657.305 us; speedup vs baseline: 1.9245x; 1.0477x over previous
//
#include <hip/hip_runtime.h>
#include <hip/hip_bf16.h>

// Problem constants
#define Bsz   16
#define Tn    2048
#define INC   80
#define Hc    512
#define Dc    512
#define NCODE 1024
#define BT    (Bsz * Tn)           // 32768
#define RECON_N (Bsz * Tn * INC)   // 2,621,440

// ---------------------------------------------------------------------------
// code_norms: CN[j] = sum_d CB[j][d]^2
// ---------------------------------------------------------------------------
__global__ __launch_bounds__(64)
void code_norms(const float* __restrict__ CB, float* __restrict__ CN) {
    int j = blockIdx.x;
    int lane = threadIdx.x;
    const float4* row = (const float4*)(CB + (size_t)j * Dc);
    float s = 0.f;
    #pragma unroll
    for (int i = 0; i < 2; ++i) {
        float4 v = row[lane + i * 64];
        s = fmaf(v.x, v.x, s);
        s = fmaf(v.y, v.y, s);
        s = fmaf(v.z, v.z, s);
        s = fmaf(v.w, v.w, s);
    }
    #pragma unroll
    for (int off = 32; off > 0; off >>= 1) s += __shfl_down(s, off, 64);
    if (lane == 0) CN[j] = s;
}

// ---------------------------------------------------------------------------
// cb_transpose: CBt[d][j] = CB[j][d].  grid (NCODE/64, Dc/64), block 256
// ---------------------------------------------------------------------------
__global__ __launch_bounds__(256)
void cb_transpose(const float* __restrict__ CB, float* __restrict__ CBt) {
    const int j0 = blockIdx.x * 64;
    const int d0 = blockIdx.y * 64;
    __shared__ float ts[64][65];
    const int tid = threadIdx.x;
    for (int i = tid; i < 4096; i += 256) {
        int r = i >> 6, c = i & 63;
        ts[r][c] = CB[(size_t)(j0 + r) * Dc + d0 + c];
    }
    __syncthreads();
    for (int i = tid; i < 4096; i += 256) {
        int r = i >> 6, c = i & 63;
        CBt[(size_t)(d0 + r) * NCODE + j0 + c] = ts[c][r];
    }
}

// ---------------------------------------------------------------------------
// mels_transpose: MT[b][c][t] = M[b][t][c].  grid (Tn/64, Bsz), block 256
// ---------------------------------------------------------------------------
__global__ __launch_bounds__(256)
void mels_transpose(const float* __restrict__ M, float* __restrict__ MT) {
    const int t0 = blockIdx.x * 64;
    const int b  = blockIdx.y;
    __shared__ float ts[64][84];
    const int tid = threadIdx.x;
    #pragma unroll
    for (int it = 0; it < 5; ++it) {
        int i = tid + it * 256;            // < 1280
        int t = i / 20, c4 = i % 20;
        *(float4*)&ts[t][c4 * 4] =
            *(const float4*)&M[((size_t)b * Tn + t0 + t) * INC + c4 * 4];
    }
    __syncthreads();
    #pragma unroll
    for (int it = 0; it < 20; ++it) {
        int i = tid + it * 256;            // < 5120
        int c = i >> 6, t = i & 63;
        MT[((size_t)b * INC + c) * Tn + t0 + t] = ts[t][c];
    }
}

// ---------------------------------------------------------------------------
// wt_transpose: Wt[(c*3+k)*Cout + o] = W[(o*Cin + c)*3 + k]
// grid (ceil(Cout/64), Cin/16), block 256
// ---------------------------------------------------------------------------
__global__ __launch_bounds__(256)
void wt_transpose(const float* __restrict__ W, float* __restrict__ Wt,
                  int Cin, int Cout) {
    const int o0 = blockIdx.x * 64;
    const int c0 = blockIdx.y * 16;
    __shared__ float ts[48][65];
    const int tid = threadIdx.x;
    for (int i = tid; i < 64 * 48; i += 256) {
        int o = i / 48, ck = i % 48;
        int oo = o0 + o;
        float v = 0.f;
        if (oo < Cout) v = W[(size_t)oo * Cin * 3 + c0 * 3 + ck];
        ts[ck][o] = v;
    }
    __syncthreads();
    for (int i = tid; i < 48 * 64; i += 256) {
        int o = i & 63, ck = i >> 6;
        int oo = o0 + o;
        if (oo < Cout) Wt[(size_t)(c0 * 3 + ck) * Cout + oo] = ts[ck][o];
    }
}

// ---------------------------------------------------------------------------
// conv_enc1: melsT [B,80,T] -> Y [B,512,T], K=3 SAME, ReLU at store.
// Tile 64 t x 128 o; per-thread 4 t x 8 o (o split {ty*4, 64+ty*4}).
// Staging now coalesced over t (melsT layout). grid (T/64, 4, B), block 256
// ---------------------------------------------------------------------------
__global__ __launch_bounds__(256)
void conv_enc1(const float* __restrict__ X, const float* __restrict__ Wt,
               const float* __restrict__ bias, float* __restrict__ Y) {
    const int t0 = blockIdx.x * 64;
    const int o0 = blockIdx.y * 128;
    const int b  = blockIdx.z;
    __shared__ __align__(16) float Xs[16][72];
    __shared__ __align__(16) float Ws[48][132];
    const int tid = threadIdx.x;
    const int tx = tid & 15, ty = tid >> 4;
    float acc[8][4] = {};   // [o8: og*4+oi][t4]
    const float* Xb = X + (size_t)b * INC * Tn;

    for (int c0 = 0; c0 < INC; c0 += 16) {
        for (int i = tid; i < 16 * 66; i += 256) {
            int cc = i / 66, tt = i % 66;
            int t = t0 + tt - 1;
            float v = 0.f;
            if (t >= 0 && t < Tn) v = Xb[(size_t)(c0 + cc) * Tn + t];
            Xs[cc][tt] = v;
        }
        for (int i = tid; i < 48 * 128; i += 256) {
            int o = i & 127, ck = i >> 7;
            Ws[ck][o] = Wt[(size_t)(c0 * 3 + ck) * Hc + o0 + o];
        }
        __syncthreads();
        #pragma unroll
        for (int cc = 0; cc < 16; ++cc) {
            float4 xa = *(const float4*)&Xs[cc][tx * 4];
            float2 xb2 = *(const float2*)&Xs[cc][tx * 4 + 4];
            float xv[6] = {xa.x, xa.y, xa.z, xa.w, xb2.x, xb2.y};
            #pragma unroll
            for (int k = 0; k < 3; ++k) {
                float4 wa = *(const float4*)&Ws[cc * 3 + k][ty * 4];
                float4 wb = *(const float4*)&Ws[cc * 3 + k][64 + ty * 4];
                float wv[8] = {wa.x, wa.y, wa.z, wa.w, wb.x, wb.y, wb.z, wb.w};
                #pragma unroll
                for (int i8 = 0; i8 < 8; ++i8)
                    #pragma unroll
                    for (int j = 0; j < 4; ++j)
                        acc[i8][j] = fmaf(wv[i8], xv[k + j], acc[i8][j]);
            }
        }
        __syncthreads();
    }
    float* Yb = Y + (size_t)b * Hc * Tn;
    #pragma unroll
    for (int og = 0; og < 2; ++og)
        #pragma unroll
        for (int oi = 0; oi < 4; ++oi) {
            int o = o0 + og * 64 + ty * 4 + oi;
            float bv = bias[o];
            const int i8 = og * 4 + oi;
            float4 r;
            r.x = fmaxf(acc[i8][0] + bv, 0.f);
            r.y = fmaxf(acc[i8][1] + bv, 0.f);
            r.z = fmaxf(acc[i8][2] + bv, 0.f);
            r.w = fmaxf(acc[i8][3] + bv, 0.f);
            *(float4*)&Yb[(size_t)o * Tn + t0 + tx * 4] = r;
        }
}

// ---------------------------------------------------------------------------
// conv_mid128cf: X [B,512,T] -> Y [B,512,T], K=3 SAME, no relu (encoder z).
// Tile 128 t x 128 o; per-thread 8 t x 8 o, conflict-free groups of 4:
// t = tx*4 + g*64 (g=0..1), o = ty*4 + og*64 (og=0..1).
// 1024 blocks = 4 blocks/CU = 4 waves/SIMD (latency hiding) + free LDS reads.
// ---------------------------------------------------------------------------
__global__ __launch_bounds__(256, 4)
void conv_mid128cf(const float* __restrict__ X, const float* __restrict__ Wt,
                   const float* __restrict__ bias, float* __restrict__ Y) {
    const int t0 = blockIdx.x * 128;
    const int o0 = blockIdx.y * 128;
    const int b  = blockIdx.z;
    __shared__ __align__(16) float Xs[16][132];   // Xs[cc][tt] = X[t0+tt-1]
    __shared__ __align__(16) float Ws[48][132];
    const int tid = threadIdx.x;
    const int tx = tid & 15, ty = tid >> 4;
    float acc[8][8] = {};   // [t: g*4+j][o: og*4+oi]
    const float* Xb = X + (size_t)b * Hc * Tn;

    for (int c0 = 0; c0 < Hc; c0 += 16) {
        for (int i = tid; i < 16 * 130; i += 256) {
            int cc = i / 130, tt = i - cc * 130;
            int t = t0 + tt - 1;
            float v = 0.f;
            if (t >= 0 && t < Tn) v = Xb[(size_t)(c0 + cc) * Tn + t];
            Xs[cc][tt] = v;
        }
        #pragma unroll
        for (int it = 0; it < 6; ++it) {
            int i = tid + it * 256;
            int ck = i >> 5, o4 = i & 31;
            *(float4*)&Ws[ck][o4 * 4] =
                *(const float4*)&Wt[(size_t)(c0 * 3 + ck) * Hc + o0 + o4 * 4];
        }
        __syncthreads();
        #pragma unroll
        for (int cc = 0; cc < 16; ++cc) {
            float xv[2][6];
            #pragma unroll
            for (int g = 0; g < 2; ++g) {
                float4 xa = *(const float4*)&Xs[cc][tx * 4 + g * 64];
                float2 xb2 = *(const float2*)&Xs[cc][tx * 4 + g * 64 + 4];
                xv[g][0] = xa.x; xv[g][1] = xa.y; xv[g][2] = xa.z;
                xv[g][3] = xa.w; xv[g][4] = xb2.x; xv[g][5] = xb2.y;
            }
            #pragma unroll
            for (int k = 0; k < 3; ++k) {
                float4 wa = *(const float4*)&Ws[cc * 3 + k][ty * 4];
                float4 wb = *(const float4*)&Ws[cc * 3 + k][64 + ty * 4];
                float wv[8] = {wa.x, wa.y, wa.z, wa.w, wb.x, wb.y, wb.z, wb.w};
                #pragma unroll
                for (int g = 0; g < 2; ++g)
                    #pragma unroll
                    for (int j = 0; j < 4; ++j) {
                        float xx = xv[g][k + j];
                        #pragma unroll
                        for (int o8 = 0; o8 < 8; ++o8)
                            acc[g * 4 + j][o8] = fmaf(wv[o8], xx, acc[g * 4 + j][o8]);
                    }
            }
        }
        __syncthreads();
    }
    float* Yb = Y + (size_t)b * Hc * Tn;
    #pragma unroll
    for (int og = 0; og < 2; ++og)
        #pragma unroll
        for (int oi = 0; oi < 4; ++oi) {
            int o = o0 + og * 64 + ty * 4 + oi;
            float bv = bias[o];
            const int o8 = og * 4 + oi;
            #pragma unroll
            for (int g = 0; g < 2; ++g) {
                float4 r;
                r.x = acc[g * 4 + 0][o8] + bv;
                r.y = acc[g * 4 + 1][o8] + bv;
                r.z = acc[g * 4 + 2][o8] + bv;
                r.w = acc[g * 4 + 3][o8] + bv;
                *(float4*)&Yb[(size_t)o * Tn + t0 + g * 64 + tx * 4] = r;
            }
        }
}

// ---------------------------------------------------------------------------
// conv_dec2p: X [B,512,T] -> partial recon (no bias), K-split over channels.
// half = blockIdx.y selects c in [half*256, half*256+256). 1024 blocks.
// Partial sums differ from single-sum fp32 only in order (recon tol is loose).
// ---------------------------------------------------------------------------
__global__ __launch_bounds__(256)
void conv_dec2p(const float* __restrict__ X, const float* __restrict__ Wt,
                float* __restrict__ P) {
    const int t0 = blockIdx.x * 64;
    const int half = blockIdx.y;
    const int b  = blockIdx.z;
    __shared__ __align__(16) float Xs[16][72];
    __shared__ __align__(16) float Ws[48][132];
    const int tid = threadIdx.x;
    const int tx = tid & 15, ty = tid >> 4;
    float acc[8][4] = {};   // [o8: og*4+oi][t4]
    const float* Xb = X + (size_t)b * Hc * Tn;
    const int cbase = half * 256;

    for (int c0 = cbase; c0 < cbase + 256; c0 += 16) {
        for (int i = tid; i < 16 * 66; i += 256) {
            int cc = i / 66, tt = i % 66;
            int t = t0 + tt - 1;
            float v = 0.f;
            if (t >= 0 && t < Tn) v = Xb[(size_t)(c0 + cc) * Tn + t];
            Xs[cc][tt] = v;
        }
        for (int i = tid; i < 48 * 128; i += 256) {
            int o = i & 127, ck = i >> 7;
            Ws[ck][o] = (o < INC) ? Wt[(size_t)(c0 * 3 + ck) * INC + o] : 0.f;
        }
        __syncthreads();
        #pragma unroll
        for (int cc = 0; cc < 16; ++cc) {
            float4 xa = *(const float4*)&Xs[cc][tx * 4];
            float2 xb2 = *(const float2*)&Xs[cc][tx * 4 + 4];
            float xv[6] = {xa.x, xa.y, xa.z, xa.w, xb2.x, xb2.y};
            #pragma unroll
            for (int k = 0; k < 3; ++k) {
                float4 wa = *(const float4*)&Ws[cc * 3 + k][ty * 4];
                float4 wb = *(const float4*)&Ws[cc * 3 + k][64 + ty * 4];
                float wv[8] = {wa.x, wa.y, wa.z, wa.w, wb.x, wb.y, wb.z, wb.w};
                #pragma unroll
                for (int i8 = 0; i8 < 8; ++i8)
                    #pragma unroll
                    for (int j = 0; j < 4; ++j)
                        acc[i8][j] = fmaf(wv[i8], xv[k + j], acc[i8][j]);
            }
        }
        __syncthreads();
    }
    float* Ph = P + (size_t)half * RECON_N;
    {
        #pragma unroll
        for (int j = 0; j < 4; ++j) {
            int t = t0 + tx * 4 + j;
            float4 s;
            s.x = acc[0][j]; s.y = acc[1][j]; s.z = acc[2][j]; s.w = acc[3][j];
            *(float4*)(Ph + ((size_t)b * Tn + t) * INC + ty * 4) = s;
        }
    }
    if (ty < 4) {
        #pragma unroll
        for (int j = 0; j < 4; ++j) {
            int t = t0 + tx * 4 + j;
            float4 s;
            s.x = acc[4][j]; s.y = acc[5][j]; s.z = acc[6][j]; s.w = acc[7][j];
            *(float4*)(Ph + ((size_t)b * Tn + t) * INC + 64 + ty * 4) = s;
        }
    }
}

// ---------------------------------------------------------------------------
// dec_combine: recon = P0 + P1 + bias. grid (RECON_N/1024), block 256, f4.
// ---------------------------------------------------------------------------
__global__ __launch_bounds__(256)
void dec_combine(const float* __restrict__ P, const float* __restrict__ bias,
                 float* __restrict__ OUT) {
    int i4 = blockIdx.x * 256 + threadIdx.x;
    float4 a = ((const float4*)P)[i4];
    float4 b = ((const float4*)(P + RECON_N))[i4];
    int o = (i4 * 4) % INC;
    float4 r;
    r.x = a.x + b.x + bias[o];
    r.y = a.y + b.y + bias[o + 1];
    r.z = a.z + b.z + bias[o + 2];
    r.w = a.w + b.w + bias[o + 3];
    ((float4*)OUT)[i4] = r;
}

// ---------------------------------------------------------------------------
// vq_partial: per code-quarter partial argmin of CN[j] - 2 z.c_j.
// grid (T/64, B, 4), block 256. Per thread: 4 positions x 16 codes.
// ---------------------------------------------------------------------------
__global__ __launch_bounds__(256)
void vq_partial(const float* __restrict__ Z, const float* __restrict__ CBt,
                const float* __restrict__ CN, float* __restrict__ candv,
                int* __restrict__ candi) {
    const int t0 = blockIdx.x * 64;
    const int b  = blockIdx.y;
    const int jbase = blockIdx.z * 256;
    const int tid = threadIdx.x;
    const int tx = tid & 15, ty = tid >> 4;
    __shared__ __align__(16) float Zs[16][68];
    __shared__ __align__(16) float Cs[16][260];
    __shared__ float rv[64][17];
    __shared__ int   ri[64][17];

    float acc[16][4] = {};   // [code16][pos]
    const float* Zb = Z + (size_t)b * Dc * Tn + t0;

    for (int d0 = 0; d0 < Dc; d0 += 16) {
        for (int i = tid; i < 1024; i += 256) {
            int dd = i >> 6, tt = i & 63;
            Zs[dd][tt] = Zb[(size_t)(d0 + dd) * Tn + tt];
        }
        for (int i = tid; i < 1024; i += 256) {
            int dd = i >> 6, j4 = i & 63;
            *(float4*)&Cs[dd][j4 * 4] =
                *(const float4*)&CBt[(size_t)(d0 + dd) * NCODE + jbase + j4 * 4];
        }
        __syncthreads();
        #pragma unroll
        for (int dd = 0; dd < 16; ++dd) {
            float4 z = *(const float4*)&Zs[dd][tx * 4];
            float zp[4] = {z.x, z.y, z.z, z.w};
            #pragma unroll
            for (int s = 0; s < 4; ++s) {
                float4 c = *(const float4*)&Cs[dd][s * 64 + ty * 4];
                float cp[4] = {c.x, c.y, c.z, c.w};
                #pragma unroll
                for (int q = 0; q < 4; ++q)
                    #pragma unroll
                    for (int p = 0; p < 4; ++p)
                        acc[s * 4 + q][p] = fmaf(cp[q], zp[p], acc[s * 4 + q][p]);
            }
        }
        __syncthreads();
    }
    float bestv[4];
    int   besti[4];
    #pragma unroll
    for (int p = 0; p < 4; ++p) { bestv[p] = 1e30f; besti[p] = 0; }
    #pragma unroll
    for (int s = 0; s < 4; ++s)
        #pragma unroll
        for (int q = 0; q < 4; ++q) {
            int j = jbase + s * 64 + ty * 4 + q;
            float cnv = CN[j];
            #pragma unroll
            for (int p = 0; p < 4; ++p) {
                float dist = fmaf(-2.f, acc[s * 4 + q][p], cnv);
                if (dist < bestv[p] || (dist == bestv[p] && j < besti[p])) {
                    bestv[p] = dist; besti[p] = j;
                }
            }
        }
    #pragma unroll
    for (int p = 0; p < 4; ++p) {
        rv[tx * 4 + p][ty] = bestv[p];
        ri[tx * 4 + p][ty] = besti[p];
    }
    __syncthreads();
    if (tid < 64) {
        float bv = rv[tid][0];
        int   bi = ri[tid][0];
        #pragma unroll
        for (int y = 1; y < 16; ++y) {
            float v = rv[tid][y];
            int   i2 = ri[tid][y];
            if (v < bv || (v == bv && i2 < bi)) { bv = v; bi = i2; }
        }
        int n = b * Tn + t0 + tid;
        candv[(size_t)blockIdx.z * BT + n] = bv;
        candi[(size_t)blockIdx.z * BT + n] = bi;
    }
}

// ---------------------------------------------------------------------------
// vq_reduce: merge 4 candidates per position. grid (BT/256), block 256
// ---------------------------------------------------------------------------
__global__ __launch_bounds__(256)
void vq_reduce(const float* __restrict__ candv, const int* __restrict__ candi,
               int* __restrict__ idxI, float* __restrict__ idxf) {
    int n = blockIdx.x * 256 + threadIdx.x;
    float bv = candv[n];
    int   bi = candi[n];
    #pragma unroll
    for (int jq = 1; jq < 4; ++jq) {
        float v = candv[(size_t)jq * BT + n];
        int   i2 = candi[(size_t)jq * BT + n];
        if (v < bv || (v == bv && i2 < bi)) { bv = v; bi = i2; }
    }
    idxI[n] = bi;
    idxf[n] = (float)bi;
}

// ---------------------------------------------------------------------------
// gemm_g: G[j][kk*512+o] = sum_c CB[j][c] * dec_w1[o][c][kk].
// grid (NCODE/64, 12): kk = y>>2, o0 = (y&3)*128. block 256, 4j x 8o.
// ---------------------------------------------------------------------------
__global__ __launch_bounds__(256)
void gemm_g(const float* __restrict__ CBt, const float* __restrict__ Wt,
            float* __restrict__ G) {
    const int j0 = blockIdx.x * 64;
    const int kk = blockIdx.y >> 2;
    const int o0 = (blockIdx.y & 3) * 128;
    __shared__ __align__(16) float As[16][68];    // [c][j]
    __shared__ __align__(16) float Bs[16][132];   // [c][o]
    const int tid = threadIdx.x;
    const int tx = tid & 15, ty = tid >> 4;
    float acc[4][8] = {};   // [j][o]

    for (int c0 = 0; c0 < Dc; c0 += 16) {
        {
            int cc = tid >> 4, j4 = tid & 15;
            *(float4*)&As[cc][j4 * 4] =
                *(const float4*)&CBt[(size_t)(c0 + cc) * NCODE + j0 + j4 * 4];
        }
        #pragma unroll
        for (int it = 0; it < 2; ++it) {
            int i = tid + it * 256;
            int cc = i >> 5, o4 = i & 31;
            *(float4*)&Bs[cc][o4 * 4] =
                *(const float4*)&Wt[(size_t)((c0 + cc) * 3 + kk) * Hc + o0 + o4 * 4];
        }
        __syncthreads();
        #pragma unroll
        for (int cc = 0; cc < 16; ++cc) {
            float4 a = *(const float4*)&As[cc][tx * 4];
            float av[4] = {a.x, a.y, a.z, a.w};
            float4 b0 = *(const float4*)&Bs[cc][ty * 4];
            float4 b1 = *(const float4*)&Bs[cc][64 + ty * 4];
            float bv[8] = {b0.x, b0.y, b0.z, b0.w, b1.x, b1.y, b1.z, b1.w};
            #pragma unroll
            for (int jj = 0; jj < 4; ++jj)
                #pragma unroll
                for (int oo = 0; oo < 8; ++oo)
                    acc[jj][oo] = fmaf(av[jj], bv[oo], acc[jj][oo]);
        }
        __syncthreads();
    }
    #pragma unroll
    for (int jj = 0; jj < 4; ++jj) {
        int j = j0 + tx * 4 + jj;
        float* gp = G + (size_t)j * 1536 + kk * 512 + o0;
        *(float4*)(gp + ty * 4) = *(float4*)&acc[jj][0];
        *(float4*)(gp + 64 + ty * 4) = *(float4*)&acc[jj][4];
    }
}

// ---------------------------------------------------------------------------
// dec_y3: y3[b][o][t] = relu(b1[o] + sum_kk G[idx[b][t+kk-1]][kk*512+o]).
// grid (T/64, 4 o-tiles, B), block 256.
// ---------------------------------------------------------------------------
__global__ __launch_bounds__(256)
void dec_y3(const int* __restrict__ idx, const float* __restrict__ G,
            const float* __restrict__ bias, float* __restrict__ Y) {
    const int t0 = blockIdx.x * 64;
    const int o0 = blockIdx.y * 128;
    const int b  = blockIdx.z;
    const int tid = threadIdx.x;
    __shared__ int sidx[66];
    __shared__ __align__(16) float Ys[128][68];

    if (tid < 66) {
        int t = t0 + tid - 1;
        sidx[tid] = (t >= 0 && t < Tn) ? idx[b * Tn + t] : -1;
    }
    __syncthreads();

    const int o = tid & 127;
    const int half = tid >> 7;
    float acc[32] = {};
    #pragma unroll
    for (int kk = 0; kk < 3; ++kk) {
        const float* Gk = G + (size_t)kk * 512 + o0 + o;
        #pragma unroll
        for (int k = 0; k < 32; ++k) {
            int j = sidx[half + 2 * k + kk];
            if (j >= 0) acc[k] += Gk[(size_t)j * 1536];
        }
    }
    float bv = bias[o0 + o];
    #pragma unroll
    for (int k = 0; k < 32; ++k)
        Ys[o][half + 2 * k] = fmaxf(acc[k] + bv, 0.f);
    __syncthreads();

    float* Yb = Y + (size_t)b * Hc * Tn + t0;
    #pragma unroll
    for (int it = 0; it < 8; ++it) {
        int i = tid + it * 256;
        int t4 = i & 15, oo = i >> 4;
        *(float4*)&Yb[(size_t)(o0 + oo) * Tn + t4 * 4] =
            *(const float4*)&Ys[oo][t4 * 4];
    }
}

// ---------------------------------------------------------------------------
extern "C" void kernel_launch(void* const* d_in, const int* in_sizes, int n_in,
                              void* d_out, int out_size, void* d_ws, size_t ws_size,
                              hipStream_t stream) {
    const float* mels    = (const float*)d_in[0];
    const float* enc_w1  = (const float*)d_in[1];
    const float* enc_b1  = (const float*)d_in[2];
    const float* enc_w2  = (const float*)d_in[3];
    const float* enc_b2  = (const float*)d_in[4];
    const float* codebook= (const float*)d_in[5];
    const float* dec_w1  = (const float*)d_in[6];
    const float* dec_b1  = (const float*)d_in[7];
    const float* dec_w2  = (const float*)d_in[8];
    const float* dec_b2  = (const float*)d_in[9];

    float* out = (float*)d_out;
    float* recon = out;                 // [B,T,80]
    float* idxf  = out + RECON_N;       // [B,T] as float

    const size_t ACT = (size_t)Bsz * Hc * Tn;   // 16,777,216 floats (64 MB)
    float* bufA = (float*)d_ws;                 // y1, later y3
    float* bufB = bufA + ACT;                   // melsT, then z, then dec partials
    int*   idxI = (int*)(bufB + ACT);           // [B*T]
    float* cn   = (float*)(idxI + BT);          // [NCODE]
    float* cbt  = cn + NCODE;                   // [512*1024]
    float* wt1  = cbt + (size_t)Dc * NCODE;     // enc_w1t: 80*3*512
    float* wt2  = wt1 + (size_t)INC * 3 * Hc;   // enc_w2t: 512*3*512
    float* wt3  = wt2 + (size_t)Hc * 3 * Dc;    // dec_w1t: 512*3*512
    float* wt4  = wt3 + (size_t)Dc * 3 * Hc;    // dec_w2t: 512*3*80
    float* candv = wt4 + (size_t)Hc * 3 * INC;  // [4*BT]
    int*   candi = (int*)(candv + 4 * BT);      // [4*BT]
    float* G    = (float*)(candi + 4 * BT);     // [1024*1536]
    float* melsT = bufB;                        // [B,80,T] (dead after enc1)
    float* Pdec  = bufB;                        // 2 partials (z dead by then)

    dim3 blk(256);
    // prep: norms + transposes (cheap, every call — graph-capture safe)
    code_norms<<<dim3(NCODE), dim3(64), 0, stream>>>(codebook, cn);
    cb_transpose<<<dim3(NCODE / 64, Dc / 64), blk, 0, stream>>>(codebook, cbt);
    mels_transpose<<<dim3(Tn / 64, Bsz), blk, 0, stream>>>(mels, melsT);
    wt_transpose<<<dim3(Hc / 64, INC / 16), blk, 0, stream>>>(enc_w1, wt1, INC, Hc);
    wt_transpose<<<dim3(Dc / 64, Hc / 16), blk, 0, stream>>>(enc_w2, wt2, Hc, Dc);
    wt_transpose<<<dim3(Hc / 64, Dc / 16), blk, 0, stream>>>(dec_w1, wt3, Dc, Hc);
    wt_transpose<<<dim3(2, Hc / 16), blk, 0, stream>>>(dec_w2, wt4, Hc, INC);
    // decoder conv1 folded matrix (independent of activations)
    gemm_g<<<dim3(NCODE / 64, 12), blk, 0, stream>>>(cbt, wt3, G);
    // encoder
    conv_enc1<<<dim3(Tn / 64, Hc / 128, Bsz), blk, 0, stream>>>(melsT, wt1, enc_b1, bufA);
    conv_mid128cf<<<dim3(Tn / 128, Dc / 128, Bsz), blk, 0, stream>>>(bufA, wt2, enc_b2, bufB);
    // vector quantization
    vq_partial<<<dim3(Tn / 64, Bsz, 4), blk, 0, stream>>>(bufB, cbt, cn, candv, candi);
    vq_reduce<<<dim3(BT / 256), blk, 0, stream>>>(candv, candi, idxI, idxf);
    // decoder: conv1 via gather of G rows, then conv2 (K-split) + combine
    dec_y3<<<dim3(Tn / 64, 4, Bsz), blk, 0, stream>>>(idxI, G, dec_b1, bufA);
    conv_dec2p<<<dim3(Tn / 64, 2, Bsz), blk, 0, stream>>>(bufA, wt4, Pdec);
    dec_combine<<<dim3(RECON_N / 1024), blk, 0, stream>>>(Pdec, dec_b2, recon);
}

// Round 6
// 1607.731 us; speedup vs baseline: 1.9838x; 1.0308x over previous
//
#include <hip/hip_runtime.h>
#include <hip/hip_bf16.h>

// Problem constants
#define Bsz   16
#define Tn    2048
#define INC   80
#define Hc    512
#define Dc    512
#define NCODE 1024
#define BT    (Bsz * Tn)           // 32768
#define RECON_N (Bsz * Tn * INC)   // 2,621,440

// ---------------------------------------------------------------------------
// code_norms: CN[j] = sum_d CB[j][d]^2
// ---------------------------------------------------------------------------
__global__ __launch_bounds__(64)
void code_norms(const float* __restrict__ CB, float* __restrict__ CN) {
    int j = blockIdx.x;
    int lane = threadIdx.x;
    const float4* row = (const float4*)(CB + (size_t)j * Dc);
    float s = 0.f;
    #pragma unroll
    for (int i = 0; i < 2; ++i) {
        float4 v = row[lane + i * 64];
        s = fmaf(v.x, v.x, s);
        s = fmaf(v.y, v.y, s);
        s = fmaf(v.z, v.z, s);
        s = fmaf(v.w, v.w, s);
    }
    #pragma unroll
    for (int off = 32; off > 0; off >>= 1) s += __shfl_down(s, off, 64);
    if (lane == 0) CN[j] = s;
}

// ---------------------------------------------------------------------------
// cb_transpose: CBt[d][j] = CB[j][d].  grid (NCODE/64, Dc/64), block 256
// ---------------------------------------------------------------------------
__global__ __launch_bounds__(256)
void cb_transpose(const float* __restrict__ CB, float* __restrict__ CBt) {
    const int j0 = blockIdx.x * 64;
    const int d0 = blockIdx.y * 64;
    __shared__ float ts[64][65];
    const int tid = threadIdx.x;
    for (int i = tid; i < 4096; i += 256) {
        int r = i >> 6, c = i & 63;
        ts[r][c] = CB[(size_t)(j0 + r) * Dc + d0 + c];
    }
    __syncthreads();
    for (int i = tid; i < 4096; i += 256) {
        int r = i >> 6, c = i & 63;
        CBt[(size_t)(d0 + r) * NCODE + j0 + c] = ts[c][r];
    }
}

// ---------------------------------------------------------------------------
// mels_transpose: MT[b][c][t] = M[b][t][c].  grid (Tn/64, Bsz), block 256
// ---------------------------------------------------------------------------
__global__ __launch_bounds__(256)
void mels_transpose(const float* __restrict__ M, float* __restrict__ MT) {
    const int t0 = blockIdx.x * 64;
    const int b  = blockIdx.y;
    __shared__ float ts[64][84];
    const int tid = threadIdx.x;
    #pragma unroll
    for (int it = 0; it < 5; ++it) {
        int i = tid + it * 256;            // < 1280
        int t = i / 20, c4 = i % 20;
        *(float4*)&ts[t][c4 * 4] =
            *(const float4*)&M[((size_t)b * Tn + t0 + t) * INC + c4 * 4];
    }
    __syncthreads();
    #pragma unroll
    for (int it = 0; it < 20; ++it) {
        int i = tid + it * 256;            // < 5120
        int c = i >> 6, t = i & 63;
        MT[((size_t)b * INC + c) * Tn + t0 + t] = ts[t][c];
    }
}

// ---------------------------------------------------------------------------
// wt_transpose: Wt[(c*3+k)*Cout + o] = W[(o*Cin + c)*3 + k]
// grid (ceil(Cout/64), Cin/16), block 256
// ---------------------------------------------------------------------------
__global__ __launch_bounds__(256)
void wt_transpose(const float* __restrict__ W, float* __restrict__ Wt,
                  int Cin, int Cout) {
    const int o0 = blockIdx.x * 64;
    const int c0 = blockIdx.y * 16;
    __shared__ float ts[48][65];
    const int tid = threadIdx.x;
    for (int i = tid; i < 64 * 48; i += 256) {
        int o = i / 48, ck = i % 48;
        int oo = o0 + o;
        float v = 0.f;
        if (oo < Cout) v = W[(size_t)oo * Cin * 3 + c0 * 3 + ck];
        ts[ck][o] = v;
    }
    __syncthreads();
    for (int i = tid; i < 48 * 64; i += 256) {
        int o = i & 63, ck = i >> 6;
        int oo = o0 + o;
        if (oo < Cout) Wt[(size_t)(c0 * 3 + ck) * Cout + oo] = ts[ck][o];
    }
}

// ---------------------------------------------------------------------------
// conv_enc1: melsT [B,80,T] -> Y [B,512,T], K=3 SAME, ReLU at store.
// Tile 64 t x 128 o; per-thread 4 t x 8 o (o split {ty*4, 64+ty*4}).
// grid (T/64, 4, B), block 256
// ---------------------------------------------------------------------------
__global__ __launch_bounds__(256)
void conv_enc1(const float* __restrict__ X, const float* __restrict__ Wt,
               const float* __restrict__ bias, float* __restrict__ Y) {
    const int t0 = blockIdx.x * 64;
    const int o0 = blockIdx.y * 128;
    const int b  = blockIdx.z;
    __shared__ __align__(16) float Xs[16][72];
    __shared__ __align__(16) float Ws[48][132];
    const int tid = threadIdx.x;
    const int tx = tid & 15, ty = tid >> 4;
    float acc[8][4] = {};   // [o8: og*4+oi][t4]
    const float* Xb = X + (size_t)b * INC * Tn;

    for (int c0 = 0; c0 < INC; c0 += 16) {
        for (int i = tid; i < 16 * 66; i += 256) {
            int cc = i / 66, tt = i % 66;
            int t = t0 + tt - 1;
            float v = 0.f;
            if (t >= 0 && t < Tn) v = Xb[(size_t)(c0 + cc) * Tn + t];
            Xs[cc][tt] = v;
        }
        for (int i = tid; i < 48 * 128; i += 256) {
            int o = i & 127, ck = i >> 7;
            Ws[ck][o] = Wt[(size_t)(c0 * 3 + ck) * Hc + o0 + o];
        }
        __syncthreads();
        #pragma unroll
        for (int cc = 0; cc < 16; ++cc) {
            float4 xa = *(const float4*)&Xs[cc][tx * 4];
            float2 xb2 = *(const float2*)&Xs[cc][tx * 4 + 4];
            float xv[6] = {xa.x, xa.y, xa.z, xa.w, xb2.x, xb2.y};
            #pragma unroll
            for (int k = 0; k < 3; ++k) {
                float4 wa = *(const float4*)&Ws[cc * 3 + k][ty * 4];
                float4 wb = *(const float4*)&Ws[cc * 3 + k][64 + ty * 4];
                float wv[8] = {wa.x, wa.y, wa.z, wa.w, wb.x, wb.y, wb.z, wb.w};
                #pragma unroll
                for (int i8 = 0; i8 < 8; ++i8)
                    #pragma unroll
                    for (int j = 0; j < 4; ++j)
                        acc[i8][j] = fmaf(wv[i8], xv[k + j], acc[i8][j]);
            }
        }
        __syncthreads();
    }
    float* Yb = Y + (size_t)b * Hc * Tn;
    #pragma unroll
    for (int og = 0; og < 2; ++og)
        #pragma unroll
        for (int oi = 0; oi < 4; ++oi) {
            int o = o0 + og * 64 + ty * 4 + oi;
            float bv = bias[o];
            const int i8 = og * 4 + oi;
            float4 r;
            r.x = fmaxf(acc[i8][0] + bv, 0.f);
            r.y = fmaxf(acc[i8][1] + bv, 0.f);
            r.z = fmaxf(acc[i8][2] + bv, 0.f);
            r.w = fmaxf(acc[i8][3] + bv, 0.f);
            *(float4*)&Yb[(size_t)o * Tn + t0 + tx * 4] = r;
        }
}

// ---------------------------------------------------------------------------
// conv_mid128cf: X [B,512,T] -> Y [B,512,T], K=3 SAME, no relu (encoder z).
// Tile 128 t x 128 o; per-thread 8 t x 8 o, conflict-free groups of 4:
// t = tx*4 + g*64 (g=0..1), o = ty*4 + og*64 (og=0..1).
// __launch_bounds__(256,2): empirically arg 4 capped VGPR at 64 -> massive
// scratch spills (r5: 962 MB WRITE_SIZE). arg 2 -> 128-VGPR cap, no spill,
// and at ~128 VGPR the HW still fits 4 waves/SIMD = 4 blocks/CU (1024-block
// grid provides exactly that).
// ---------------------------------------------------------------------------
__global__ __launch_bounds__(256, 2)
void conv_mid128cf(const float* __restrict__ X, const float* __restrict__ Wt,
                   const float* __restrict__ bias, float* __restrict__ Y) {
    const int t0 = blockIdx.x * 128;
    const int o0 = blockIdx.y * 128;
    const int b  = blockIdx.z;
    __shared__ __align__(16) float Xs[16][132];   // Xs[cc][tt] = X[t0+tt-1]
    __shared__ __align__(16) float Ws[48][132];
    const int tid = threadIdx.x;
    const int tx = tid & 15, ty = tid >> 4;
    float acc[8][8] = {};   // [t: g*4+j][o: og*4+oi]
    const float* Xb = X + (size_t)b * Hc * Tn;

    for (int c0 = 0; c0 < Hc; c0 += 16) {
        for (int i = tid; i < 16 * 130; i += 256) {
            int cc = i / 130, tt = i - cc * 130;
            int t = t0 + tt - 1;
            float v = 0.f;
            if (t >= 0 && t < Tn) v = Xb[(size_t)(c0 + cc) * Tn + t];
            Xs[cc][tt] = v;
        }
        #pragma unroll
        for (int it = 0; it < 6; ++it) {
            int i = tid + it * 256;
            int ck = i >> 5, o4 = i & 31;
            *(float4*)&Ws[ck][o4 * 4] =
                *(const float4*)&Wt[(size_t)(c0 * 3 + ck) * Hc + o0 + o4 * 4];
        }
        __syncthreads();
        #pragma unroll
        for (int cc = 0; cc < 16; ++cc) {
            float xv[2][6];
            #pragma unroll
            for (int g = 0; g < 2; ++g) {
                float4 xa = *(const float4*)&Xs[cc][tx * 4 + g * 64];
                float2 xb2 = *(const float2*)&Xs[cc][tx * 4 + g * 64 + 4];
                xv[g][0] = xa.x; xv[g][1] = xa.y; xv[g][2] = xa.z;
                xv[g][3] = xa.w; xv[g][4] = xb2.x; xv[g][5] = xb2.y;
            }
            #pragma unroll
            for (int k = 0; k < 3; ++k) {
                float4 wa = *(const float4*)&Ws[cc * 3 + k][ty * 4];
                float4 wb = *(const float4*)&Ws[cc * 3 + k][64 + ty * 4];
                float wv[8] = {wa.x, wa.y, wa.z, wa.w, wb.x, wb.y, wb.z, wb.w};
                #pragma unroll
                for (int g = 0; g < 2; ++g)
                    #pragma unroll
                    for (int j = 0; j < 4; ++j) {
                        float xx = xv[g][k + j];
                        #pragma unroll
                        for (int o8 = 0; o8 < 8; ++o8)
                            acc[g * 4 + j][o8] = fmaf(wv[o8], xx, acc[g * 4 + j][o8]);
                    }
            }
        }
        __syncthreads();
    }
    float* Yb = Y + (size_t)b * Hc * Tn;
    #pragma unroll
    for (int og = 0; og < 2; ++og)
        #pragma unroll
        for (int oi = 0; oi < 4; ++oi) {
            int o = o0 + og * 64 + ty * 4 + oi;
            float bv = bias[o];
            const int o8 = og * 4 + oi;
            #pragma unroll
            for (int g = 0; g < 2; ++g) {
                float4 r;
                r.x = acc[g * 4 + 0][o8] + bv;
                r.y = acc[g * 4 + 1][o8] + bv;
                r.z = acc[g * 4 + 2][o8] + bv;
                r.w = acc[g * 4 + 3][o8] + bv;
                *(float4*)&Yb[(size_t)o * Tn + t0 + g * 64 + tx * 4] = r;
            }
        }
}

// ---------------------------------------------------------------------------
// conv_dec2p: X [B,512,T] -> partial recon (no bias), K-split over channels.
// half = blockIdx.y selects c in [half*256, half*256+256). 1024 blocks.
// ---------------------------------------------------------------------------
__global__ __launch_bounds__(256)
void conv_dec2p(const float* __restrict__ X, const float* __restrict__ Wt,
                float* __restrict__ P) {
    const int t0 = blockIdx.x * 64;
    const int half = blockIdx.y;
    const int b  = blockIdx.z;
    __shared__ __align__(16) float Xs[16][72];
    __shared__ __align__(16) float Ws[48][132];
    const int tid = threadIdx.x;
    const int tx = tid & 15, ty = tid >> 4;
    float acc[8][4] = {};   // [o8: og*4+oi][t4]
    const float* Xb = X + (size_t)b * Hc * Tn;
    const int cbase = half * 256;

    for (int c0 = cbase; c0 < cbase + 256; c0 += 16) {
        for (int i = tid; i < 16 * 66; i += 256) {
            int cc = i / 66, tt = i % 66;
            int t = t0 + tt - 1;
            float v = 0.f;
            if (t >= 0 && t < Tn) v = Xb[(size_t)(c0 + cc) * Tn + t];
            Xs[cc][tt] = v;
        }
        for (int i = tid; i < 48 * 128; i += 256) {
            int o = i & 127, ck = i >> 7;
            Ws[ck][o] = (o < INC) ? Wt[(size_t)(c0 * 3 + ck) * INC + o] : 0.f;
        }
        __syncthreads();
        #pragma unroll
        for (int cc = 0; cc < 16; ++cc) {
            float4 xa = *(const float4*)&Xs[cc][tx * 4];
            float2 xb2 = *(const float2*)&Xs[cc][tx * 4 + 4];
            float xv[6] = {xa.x, xa.y, xa.z, xa.w, xb2.x, xb2.y};
            #pragma unroll
            for (int k = 0; k < 3; ++k) {
                float4 wa = *(const float4*)&Ws[cc * 3 + k][ty * 4];
                float4 wb = *(const float4*)&Ws[cc * 3 + k][64 + ty * 4];
                float wv[8] = {wa.x, wa.y, wa.z, wa.w, wb.x, wb.y, wb.z, wb.w};
                #pragma unroll
                for (int i8 = 0; i8 < 8; ++i8)
                    #pragma unroll
                    for (int j = 0; j < 4; ++j)
                        acc[i8][j] = fmaf(wv[i8], xv[k + j], acc[i8][j]);
            }
        }
        __syncthreads();
    }
    float* Ph = P + (size_t)half * RECON_N;
    {
        #pragma unroll
        for (int j = 0; j < 4; ++j) {
            int t = t0 + tx * 4 + j;
            float4 s;
            s.x = acc[0][j]; s.y = acc[1][j]; s.z = acc[2][j]; s.w = acc[3][j];
            *(float4*)(Ph + ((size_t)b * Tn + t) * INC + ty * 4) = s;
        }
    }
    if (ty < 4) {
        #pragma unroll
        for (int j = 0; j < 4; ++j) {
            int t = t0 + tx * 4 + j;
            float4 s;
            s.x = acc[4][j]; s.y = acc[5][j]; s.z = acc[6][j]; s.w = acc[7][j];
            *(float4*)(Ph + ((size_t)b * Tn + t) * INC + 64 + ty * 4) = s;
        }
    }
}

// ---------------------------------------------------------------------------
// dec_combine: recon = P0 + P1 + bias. grid (RECON_N/1024), block 256, f4.
// ---------------------------------------------------------------------------
__global__ __launch_bounds__(256)
void dec_combine(const float* __restrict__ P, const float* __restrict__ bias,
                 float* __restrict__ OUT) {
    int i4 = blockIdx.x * 256 + threadIdx.x;
    float4 a = ((const float4*)P)[i4];
    float4 b = ((const float4*)(P + RECON_N))[i4];
    int o = (i4 * 4) % INC;
    float4 r;
    r.x = a.x + b.x + bias[o];
    r.y = a.y + b.y + bias[o + 1];
    r.z = a.z + b.z + bias[o + 2];
    r.w = a.w + b.w + bias[o + 3];
    ((float4*)OUT)[i4] = r;
}

// ---------------------------------------------------------------------------
// vq_partial: per code-quarter partial argmin of CN[j] - 2 z.c_j.
// grid (T/64, B, 4), block 256. Per thread: 4 positions x 16 codes.
// ---------------------------------------------------------------------------
__global__ __launch_bounds__(256)
void vq_partial(const float* __restrict__ Z, const float* __restrict__ CBt,
                const float* __restrict__ CN, float* __restrict__ candv,
                int* __restrict__ candi) {
    const int t0 = blockIdx.x * 64;
    const int b  = blockIdx.y;
    const int jbase = blockIdx.z * 256;
    const int tid = threadIdx.x;
    const int tx = tid & 15, ty = tid >> 4;
    __shared__ __align__(16) float Zs[16][68];
    __shared__ __align__(16) float Cs[16][260];
    __shared__ float rv[64][17];
    __shared__ int   ri[64][17];

    float acc[16][4] = {};   // [code16][pos]
    const float* Zb = Z + (size_t)b * Dc * Tn + t0;

    for (int d0 = 0; d0 < Dc; d0 += 16) {
        for (int i = tid; i < 1024; i += 256) {
            int dd = i >> 6, tt = i & 63;
            Zs[dd][tt] = Zb[(size_t)(d0 + dd) * Tn + tt];
        }
        for (int i = tid; i < 1024; i += 256) {
            int dd = i >> 6, j4 = i & 63;
            *(float4*)&Cs[dd][j4 * 4] =
                *(const float4*)&CBt[(size_t)(d0 + dd) * NCODE + jbase + j4 * 4];
        }
        __syncthreads();
        #pragma unroll
        for (int dd = 0; dd < 16; ++dd) {
            float4 z = *(const float4*)&Zs[dd][tx * 4];
            float zp[4] = {z.x, z.y, z.z, z.w};
            #pragma unroll
            for (int s = 0; s < 4; ++s) {
                float4 c = *(const float4*)&Cs[dd][s * 64 + ty * 4];
                float cp[4] = {c.x, c.y, c.z, c.w};
                #pragma unroll
                for (int q = 0; q < 4; ++q)
                    #pragma unroll
                    for (int p = 0; p < 4; ++p)
                        acc[s * 4 + q][p] = fmaf(cp[q], zp[p], acc[s * 4 + q][p]);
            }
        }
        __syncthreads();
    }
    float bestv[4];
    int   besti[4];
    #pragma unroll
    for (int p = 0; p < 4; ++p) { bestv[p] = 1e30f; besti[p] = 0; }
    #pragma unroll
    for (int s = 0; s < 4; ++s)
        #pragma unroll
        for (int q = 0; q < 4; ++q) {
            int j = jbase + s * 64 + ty * 4 + q;
            float cnv = CN[j];
            #pragma unroll
            for (int p = 0; p < 4; ++p) {
                float dist = fmaf(-2.f, acc[s * 4 + q][p], cnv);
                if (dist < bestv[p] || (dist == bestv[p] && j < besti[p])) {
                    bestv[p] = dist; besti[p] = j;
                }
            }
        }
    #pragma unroll
    for (int p = 0; p < 4; ++p) {
        rv[tx * 4 + p][ty] = bestv[p];
        ri[tx * 4 + p][ty] = besti[p];
    }
    __syncthreads();
    if (tid < 64) {
        float bv = rv[tid][0];
        int   bi = ri[tid][0];
        #pragma unroll
        for (int y = 1; y < 16; ++y) {
            float v = rv[tid][y];
            int   i2 = ri[tid][y];
            if (v < bv || (v == bv && i2 < bi)) { bv = v; bi = i2; }
        }
        int n = b * Tn + t0 + tid;
        candv[(size_t)blockIdx.z * BT + n] = bv;
        candi[(size_t)blockIdx.z * BT + n] = bi;
    }
}

// ---------------------------------------------------------------------------
// vq_reduce: merge 4 candidates per position. grid (BT/256), block 256
// ---------------------------------------------------------------------------
__global__ __launch_bounds__(256)
void vq_reduce(const float* __restrict__ candv, const int* __restrict__ candi,
               int* __restrict__ idxI, float* __restrict__ idxf) {
    int n = blockIdx.x * 256 + threadIdx.x;
    float bv = candv[n];
    int   bi = candi[n];
    #pragma unroll
    for (int jq = 1; jq < 4; ++jq) {
        float v = candv[(size_t)jq * BT + n];
        int   i2 = candi[(size_t)jq * BT + n];
        if (v < bv || (v == bv && i2 < bi)) { bv = v; bi = i2; }
    }
    idxI[n] = bi;
    idxf[n] = (float)bi;
}

// ---------------------------------------------------------------------------
// gemm_g: G[j][kk*512+o] = sum_c CB[j][c] * dec_w1[o][c][kk].
// grid (NCODE/64, 12): kk = y>>2, o0 = (y&3)*128. block 256, 4j x 8o.
// ---------------------------------------------------------------------------
__global__ __launch_bounds__(256)
void gemm_g(const float* __restrict__ CBt, const float* __restrict__ Wt,
            float* __restrict__ G) {
    const int j0 = blockIdx.x * 64;
    const int kk = blockIdx.y >> 2;
    const int o0 = (blockIdx.y & 3) * 128;
    __shared__ __align__(16) float As[16][68];    // [c][j]
    __shared__ __align__(16) float Bs[16][132];   // [c][o]
    const int tid = threadIdx.x;
    const int tx = tid & 15, ty = tid >> 4;
    float acc[4][8] = {};   // [j][o]

    for (int c0 = 0; c0 < Dc; c0 += 16) {
        {
            int cc = tid >> 4, j4 = tid & 15;
            *(float4*)&As[cc][j4 * 4] =
                *(const float4*)&CBt[(size_t)(c0 + cc) * NCODE + j0 + j4 * 4];
        }
        #pragma unroll
        for (int it = 0; it < 2; ++it) {
            int i = tid + it * 256;
            int cc = i >> 5, o4 = i & 31;
            *(float4*)&Bs[cc][o4 * 4] =
                *(const float4*)&Wt[(size_t)((c0 + cc) * 3 + kk) * Hc + o0 + o4 * 4];
        }
        __syncthreads();
        #pragma unroll
        for (int cc = 0; cc < 16; ++cc) {
            float4 a = *(const float4*)&As[cc][tx * 4];
            float av[4] = {a.x, a.y, a.z, a.w};
            float4 b0 = *(const float4*)&Bs[cc][ty * 4];
            float4 b1 = *(const float4*)&Bs[cc][64 + ty * 4];
            float bv[8] = {b0.x, b0.y, b0.z, b0.w, b1.x, b1.y, b1.z, b1.w};
            #pragma unroll
            for (int jj = 0; jj < 4; ++jj)
                #pragma unroll
                for (int oo = 0; oo < 8; ++oo)
                    acc[jj][oo] = fmaf(av[jj], bv[oo], acc[jj][oo]);
        }
        __syncthreads();
    }
    #pragma unroll
    for (int jj = 0; jj < 4; ++jj) {
        int j = j0 + tx * 4 + jj;
        float* gp = G + (size_t)j * 1536 + kk * 512 + o0;
        *(float4*)(gp + ty * 4) = *(float4*)&acc[jj][0];
        *(float4*)(gp + 64 + ty * 4) = *(float4*)&acc[jj][4];
    }
}

// ---------------------------------------------------------------------------
// dec_y3: y3[b][o][t] = relu(b1[o] + sum_kk G[idx[b][t+kk-1]][kk*512+o]).
// grid (T/64, 4 o-tiles, B), block 256.
// ---------------------------------------------------------------------------
__global__ __launch_bounds__(256)
void dec_y3(const int* __restrict__ idx, const float* __restrict__ G,
            const float* __restrict__ bias, float* __restrict__ Y) {
    const int t0 = blockIdx.x * 64;
    const int o0 = blockIdx.y * 128;
    const int b  = blockIdx.z;
    const int tid = threadIdx.x;
    __shared__ int sidx[66];
    __shared__ __align__(16) float Ys[128][68];

    if (tid < 66) {
        int t = t0 + tid - 1;
        sidx[tid] = (t >= 0 && t < Tn) ? idx[b * Tn + t] : -1;
    }
    __syncthreads();

    const int o = tid & 127;
    const int half = tid >> 7;
    float acc[32] = {};
    #pragma unroll
    for (int kk = 0; kk < 3; ++kk) {
        const float* Gk = G + (size_t)kk * 512 + o0 + o;
        #pragma unroll
        for (int k = 0; k < 32; ++k) {
            int j = sidx[half + 2 * k + kk];
            if (j >= 0) acc[k] += Gk[(size_t)j * 1536];
        }
    }
    float bv = bias[o0 + o];
    #pragma unroll
    for (int k = 0; k < 32; ++k)
        Ys[o][half + 2 * k] = fmaxf(acc[k] + bv, 0.f);
    __syncthreads();

    float* Yb = Y + (size_t)b * Hc * Tn + t0;
    #pragma unroll
    for (int it = 0; it < 8; ++it) {
        int i = tid + it * 256;
        int t4 = i & 15, oo = i >> 4;
        *(float4*)&Yb[(size_t)(o0 + oo) * Tn + t4 * 4] =
            *(const float4*)&Ys[oo][t4 * 4];
    }
}

// ---------------------------------------------------------------------------
extern "C" void kernel_launch(void* const* d_in, const int* in_sizes, int n_in,
                              void* d_out, int out_size, void* d_ws, size_t ws_size,
                              hipStream_t stream) {
    const float* mels    = (const float*)d_in[0];
    const float* enc_w1  = (const float*)d_in[1];
    const float* enc_b1  = (const float*)d_in[2];
    const float* enc_w2  = (const float*)d_in[3];
    const float* enc_b2  = (const float*)d_in[4];
    const float* codebook= (const float*)d_in[5];
    const float* dec_w1  = (const float*)d_in[6];
    const float* dec_b1  = (const float*)d_in[7];
    const float* dec_w2  = (const float*)d_in[8];
    const float* dec_b2  = (const float*)d_in[9];

    float* out = (float*)d_out;
    float* recon = out;                 // [B,T,80]
    float* idxf  = out + RECON_N;       // [B,T] as float

    const size_t ACT = (size_t)Bsz * Hc * Tn;   // 16,777,216 floats (64 MB)
    float* bufA = (float*)d_ws;                 // y1, later y3
    float* bufB = bufA + ACT;                   // melsT, then z, then dec partials
    int*   idxI = (int*)(bufB + ACT);           // [B*T]
    float* cn   = (float*)(idxI + BT);          // [NCODE]
    float* cbt  = cn + NCODE;                   // [512*1024]
    float* wt1  = cbt + (size_t)Dc * NCODE;     // enc_w1t: 80*3*512
    float* wt2  = wt1 + (size_t)INC * 3 * Hc;   // enc_w2t: 512*3*512
    float* wt3  = wt2 + (size_t)Hc * 3 * Dc;    // dec_w1t: 512*3*512
    float* wt4  = wt3 + (size_t)Dc * 3 * Hc;    // dec_w2t: 512*3*80
    float* candv = wt4 + (size_t)Hc * 3 * INC;  // [4*BT]
    int*   candi = (int*)(candv + 4 * BT);      // [4*BT]
    float* G    = (float*)(candi + 4 * BT);     // [1024*1536]
    float* melsT = bufB;                        // [B,80,T] (dead after enc1)
    float* Pdec  = bufB;                        // 2 partials (z dead by then)

    dim3 blk(256);
    // prep: norms + transposes (cheap, every call — graph-capture safe)
    code_norms<<<dim3(NCODE), dim3(64), 0, stream>>>(codebook, cn);
    cb_transpose<<<dim3(NCODE / 64, Dc / 64), blk, 0, stream>>>(codebook, cbt);
    mels_transpose<<<dim3(Tn / 64, Bsz), blk, 0, stream>>>(mels, melsT);
    wt_transpose<<<dim3(Hc / 64, INC / 16), blk, 0, stream>>>(enc_w1, wt1, INC, Hc);
    wt_transpose<<<dim3(Dc / 64, Hc / 16), blk, 0, stream>>>(enc_w2, wt2, Hc, Dc);
    wt_transpose<<<dim3(Hc / 64, Dc / 16), blk, 0, stream>>>(dec_w1, wt3, Dc, Hc);
    wt_transpose<<<dim3(2, Hc / 16), blk, 0, stream>>>(dec_w2, wt4, Hc, INC);
    // decoder conv1 folded matrix (independent of activations)
    gemm_g<<<dim3(NCODE / 64, 12), blk, 0, stream>>>(cbt, wt3, G);
    // encoder
    conv_enc1<<<dim3(Tn / 64, Hc / 128, Bsz), blk, 0, stream>>>(melsT, wt1, enc_b1, bufA);
    conv_mid128cf<<<dim3(Tn / 128, Dc / 128, Bsz), blk, 0, stream>>>(bufA, wt2, enc_b2, bufB);
    // vector quantization
    vq_partial<<<dim3(Tn / 64, Bsz, 4), blk, 0, stream>>>(bufB, cbt, cn, candv, candi);
    vq_reduce<<<dim3(BT / 256), blk, 0, stream>>>(candv, candi, idxI, idxf);
    // decoder: conv1 via gather of G rows, then conv2 (K-split) + combine
    dec_y3<<<dim3(Tn / 64, 4, Bsz), blk, 0, stream>>>(idxI, G, dec_b1, bufA);
    conv_dec2p<<<dim3(Tn / 64, 2, Bsz), blk, 0, stream>>>(bufA, wt4, Pdec);
    dec_combine<<<dim3(RECON_N / 1024), blk, 0, stream>>>(Pdec, dec_b2, recon);
}